// Round 1
// baseline (808.728 us; speedup 1.0000x reference)
//
#include <hip/hip_runtime.h>
#include <hip/hip_fp16.h>

// Sinkhorn OT loss, MI355X.
// n=2000 topics, m=20000 vocab. K=exp(-20*M). Up to 100 iterations, early-stop
// checks at cpt=1 and cpt=51 (reference updates err only when cpt%50==1).
// Fixed launch sequence; device-side `done` flag makes converged iterations no-ops.

#define N_ROWS 2000
#define M_COLS 20000
#define M4C 5000          // M_COLS / 4

__device__ __constant__ const float ALPHA = 20.0f;

constexpr float A_MARG = 1.0f / 2000.0f;
constexpr float B_MARG = 1.0f / 20000.0f;
constexpr float EPSV   = 1e-16f;
constexpr float THR    = 0.005f;

// ---- block reduction (256 threads = 4 waves of 64) ----
__device__ __forceinline__ float block_reduce_sum(float v) {
#pragma unroll
    for (int o = 32; o > 0; o >>= 1) v += __shfl_down(v, o, 64);
    __shared__ float smem[4];
    int lane = threadIdx.x & 63;
    int w    = threadIdx.x >> 6;
    if (lane == 0) smem[w] = v;
    __syncthreads();
    v = (threadIdx.x < 4) ? smem[threadIdx.x] : 0.0f;
    v += __shfl_down(v, 2, 64);
    v += __shfl_down(v, 1, 64);
    return v;   // valid in thread 0
}

// ---- init: done=0, err=0, loss=0, u=1/n, vden=0 ----
__global__ __launch_bounds__(256) void init_kernel(float* __restrict__ u,
                                                   float* __restrict__ vden,
                                                   int* done, float* err, double* loss) {
    int idx = blockIdx.x * 256 + threadIdx.x;
    if (idx == 0) { *done = 0; *err = 0.0f; *loss = 0.0; }
    if (idx < N_ROWS) u[idx] = A_MARG;
    if (idx < M_COLS) vden[idx] = 0.0f;
}

// ---- precompute K as fp16 (4 halves packed in a float2) ----
__global__ __launch_bounds__(256) void buildK_kernel(const float* __restrict__ M,
                                                     float2* __restrict__ K4) {
    size_t stride = (size_t)gridDim.x * 256;
    size_t total  = (size_t)N_ROWS * M4C;
    for (size_t i = (size_t)blockIdx.x * 256 + threadIdx.x; i < total; i += stride) {
        float4 mm = reinterpret_cast<const float4*>(M)[i];
        __half2 h0, h1;
        h0.x = __float2half(expf(-ALPHA * mm.x));
        h0.y = __float2half(expf(-ALPHA * mm.y));
        h1.x = __float2half(expf(-ALPHA * mm.z));
        h1.y = __float2half(expf(-ALPHA * mm.w));
        float2 out;
        out.x = __builtin_bit_cast(float, h0);
        out.y = __builtin_bit_cast(float, h1);
        K4[i] = out;
    }
}

// ---- column pass: vden_j += sum_i K[i][j] * u[i]  (split-K over rows, atomics) ----
// grid: (20 col-tiles, 40 row-chunks of 50 rows), block 256; thread owns 4 columns.
template <bool USEK>
__global__ __launch_bounds__(256) void colpass_kernel(const float* __restrict__ M,
                                                      const float2* __restrict__ K4,
                                                      const float* __restrict__ u,
                                                      float* __restrict__ vden,
                                                      const int* __restrict__ done) {
    if (*done) return;
    int c4 = blockIdx.x * 256 + threadIdx.x;
    if (c4 >= M4C) return;
    int r0 = blockIdx.y * 50;
    float4 acc = make_float4(0.f, 0.f, 0.f, 0.f);
    for (int r = r0; r < r0 + 50; ++r) {
        float ui = u[r];  // uniform across block -> L1 broadcast
        if (USEK) {
            float2 raw = K4[(size_t)r * M4C + c4];
            __half2 h0 = __builtin_bit_cast(__half2, raw.x);
            __half2 h1 = __builtin_bit_cast(__half2, raw.y);
            acc.x += __low2float(h0)  * ui;
            acc.y += __high2float(h0) * ui;
            acc.z += __low2float(h1)  * ui;
            acc.w += __high2float(h1) * ui;
        } else {
            float4 mm = reinterpret_cast<const float4*>(M)[(size_t)r * M4C + c4];
            acc.x += expf(-ALPHA * mm.x) * ui;
            acc.y += expf(-ALPHA * mm.y) * ui;
            acc.z += expf(-ALPHA * mm.z) * ui;
            acc.w += expf(-ALPHA * mm.w) * ui;
        }
    }
    atomicAdd(&vden[c4 * 4 + 0], acc.x);
    atomicAdd(&vden[c4 * 4 + 1], acc.y);
    atomicAdd(&vden[c4 * 4 + 2], acc.z);
    atomicAdd(&vden[c4 * 4 + 3], acc.w);
}

// ---- v_j = b / (vden_j + eps); reset vden for next accumulation ----
__global__ __launch_bounds__(256) void finalize_v_kernel(float* __restrict__ v,
                                                         float* __restrict__ vden,
                                                         const int* __restrict__ done) {
    if (*done) return;
    int j = blockIdx.x * 256 + threadIdx.x;
    if (j < M_COLS) {
        v[j] = B_MARG / (vden[j] + EPSV);
        vden[j] = 0.0f;
    }
}

// ---- row pass: u_i = a / (sum_j K[i][j]*v[j] + eps). block per row. ----
template <bool USEK>
__global__ __launch_bounds__(256) void rowpass_kernel(const float* __restrict__ M,
                                                      const float2* __restrict__ K4,
                                                      const float* __restrict__ v,
                                                      float* __restrict__ u,
                                                      const int* __restrict__ done) {
    if (*done) return;
    int row = blockIdx.x;
    const float4* v4 = reinterpret_cast<const float4*>(v);
    float acc = 0.0f;
    for (int c4 = threadIdx.x; c4 < M4C; c4 += 256) {
        float4 vv = v4[c4];
        float kx, ky, kz, kw;
        if (USEK) {
            float2 raw = K4[(size_t)row * M4C + c4];
            __half2 h0 = __builtin_bit_cast(__half2, raw.x);
            __half2 h1 = __builtin_bit_cast(__half2, raw.y);
            kx = __low2float(h0);  ky = __high2float(h0);
            kz = __low2float(h1);  kw = __high2float(h1);
        } else {
            float4 mm = reinterpret_cast<const float4*>(M)[(size_t)row * M4C + c4];
            kx = expf(-ALPHA * mm.x); ky = expf(-ALPHA * mm.y);
            kz = expf(-ALPHA * mm.z); kw = expf(-ALPHA * mm.w);
        }
        acc += kx * vv.x + ky * vv.y + kz * vv.z + kw * vv.w;
    }
    float s = block_reduce_sum(acc);
    if (threadIdx.x == 0) u[row] = A_MARG / (s + EPSV);
}

// ---- err = sum_j | v_j * (K^T u)_j - b | ; (K^T u) is in vden; reset vden ----
__global__ __launch_bounds__(256) void errfin_kernel(const float* __restrict__ v,
                                                     float* __restrict__ vden,
                                                     float* __restrict__ err,
                                                     const int* __restrict__ done) {
    if (*done) return;
    int j = blockIdx.x * 256 + threadIdx.x;
    float local = 0.0f;
    if (j < M_COLS) {
        local = fabsf(v[j] * vden[j] - B_MARG);
        vden[j] = 0.0f;
    }
    float s = block_reduce_sum(local);
    if (threadIdx.x == 0) atomicAdd(err, s);
}

// ---- check convergence: if err <= thr, set done; always reset err ----
__global__ void check_kernel(int* done, float* err) {
    if (threadIdx.x == 0) {
        if (!*done && *err <= THR) *done = 1;
        *err = 0.0f;
    }
}

// ---- loss = sum_ij u_i * K_ij * v_j * M_ij  (fp32 K from M; fp64 combine) ----
__global__ __launch_bounds__(256) void losspass_kernel(const float* __restrict__ M,
                                                       const float* __restrict__ u,
                                                       const float* __restrict__ v,
                                                       double* __restrict__ loss) {
    int row = blockIdx.x;
    const float4* M4p = reinterpret_cast<const float4*>(M + (size_t)row * M_COLS);
    const float4* v4  = reinterpret_cast<const float4*>(v);
    float acc = 0.0f;
    for (int c4 = threadIdx.x; c4 < M4C; c4 += 256) {
        float4 mm = M4p[c4];
        float4 vv = v4[c4];
        acc += expf(-ALPHA * mm.x) * vv.x * mm.x;
        acc += expf(-ALPHA * mm.y) * vv.y * mm.y;
        acc += expf(-ALPHA * mm.z) * vv.z * mm.z;
        acc += expf(-ALPHA * mm.w) * vv.w * mm.w;
    }
    float s = block_reduce_sum(acc);
    if (threadIdx.x == 0) atomicAdd(loss, (double)s * (double)u[row]);
}

__global__ void writeout_kernel(float* __restrict__ out, const double* __restrict__ loss) {
    if (threadIdx.x == 0) out[0] = (float)(*loss * 100.0);
}

extern "C" void kernel_launch(void* const* d_in, const int* in_sizes, int n_in,
                              void* d_out, int out_size, void* d_ws, size_t ws_size,
                              hipStream_t stream) {
    const float* M = (const float*)d_in[0];
    char* base = (char*)d_ws;

    int*    done = (int*)(base + 0);
    float*  err  = (float*)(base + 8);
    double* loss = (double*)(base + 16);
    float*  u    = (float*)(base + 64);                    // 2000 f -> 8000 B (pad to 8192)
    float*  v    = (float*)(base + 64 + 8192);             // 20000 f -> 80000 B
    float*  vden = (float*)(base + 64 + 8192 + 80000);     // 20000 f -> 80000 B
    size_t  k_off = ((size_t)(64 + 8192 + 80000 + 80000) + 255) & ~(size_t)255;
    float2* K4   = (float2*)(base + k_off);
    size_t  k_bytes = (size_t)N_ROWS * M_COLS * sizeof(__half);
    const bool useK = ws_size >= k_off + k_bytes;

    init_kernel<<<79, 256, 0, stream>>>(u, vden, done, err, loss);
    if (useK) buildK_kernel<<<4096, 256, 0, stream>>>(M, K4);

    dim3 cgrid(20, 40);  // 20 col-tiles x 40 row-chunks (50 rows each)
    for (int t = 1; t <= 100; ++t) {
        if (useK) colpass_kernel<true ><<<cgrid, 256, 0, stream>>>(M, K4, u, vden, done);
        else      colpass_kernel<false><<<cgrid, 256, 0, stream>>>(M, K4, u, vden, done);
        finalize_v_kernel<<<79, 256, 0, stream>>>(v, vden, done);
        if (useK) rowpass_kernel<true ><<<N_ROWS, 256, 0, stream>>>(M, K4, v, u, done);
        else      rowpass_kernel<false><<<N_ROWS, 256, 0, stream>>>(M, K4, v, u, done);
        if (t == 1 || t == 51) {
            if (useK) colpass_kernel<true ><<<cgrid, 256, 0, stream>>>(M, K4, u, vden, done);
            else      colpass_kernel<false><<<cgrid, 256, 0, stream>>>(M, K4, u, vden, done);
            errfin_kernel<<<79, 256, 0, stream>>>(v, vden, err, done);
            check_kernel<<<1, 64, 0, stream>>>(done, err);
        }
    }
    losspass_kernel<<<N_ROWS, 256, 0, stream>>>(M, u, v, loss);
    writeout_kernel<<<1, 64, 0, stream>>>((float*)d_out, loss);
}

// Round 2
// 524.760 us; speedup vs baseline: 1.5411x; 1.5411x over previous
//
#include <hip/hip_runtime.h>
#include <hip/hip_fp16.h>

typedef unsigned int uint32;
typedef float floatx2 __attribute__((ext_vector_type(2)));

#define ROWS_R 2000
#define COLS_R 20000
#define ROWS_P 2048
#define COLS_P 20480
#define DWC_P  (COLS_P/4)   /* 5120 dwords per padded row  */
#define DWR_P  (ROWS_P/4)   /* 512 dwords per padded col   */
#define NBLK   256
#define NTHR   1024
#define NWAVE  16

static constexpr float A_MARG = 1.0f / 2000.0f;
static constexpr float B_MARG = 1.0f / 20000.0f;
static constexpr float EPSV   = 1e-16f;
static constexpr float THR    = 0.005f;
static constexpr float NALPHA = -20.0f;

// ============================ persistent-path kernels ============================

// ---- grid barrier: sense-reversing, agent-scope atomics. ctrl[0]=count, ctrl[32]=gen ----
__device__ __forceinline__ void grid_barrier(uint32* cnt, uint32* gen) {
    __syncthreads();
    if (threadIdx.x == 0) {
        uint32 g = __hip_atomic_load(gen, __ATOMIC_RELAXED, __HIP_MEMORY_SCOPE_AGENT);
        __threadfence();  // release: wbl2 — publish this XCD's dirty lines
        uint32 arrived = __hip_atomic_fetch_add(cnt, 1u, __ATOMIC_ACQ_REL, __HIP_MEMORY_SCOPE_AGENT);
        if (arrived == NBLK - 1) {
            __hip_atomic_store(cnt, 0u, __ATOMIC_RELAXED, __HIP_MEMORY_SCOPE_AGENT);
            __hip_atomic_fetch_add(gen, 1u, __ATOMIC_RELEASE, __HIP_MEMORY_SCOPE_AGENT);
        } else {
            while (__hip_atomic_load(gen, __ATOMIC_ACQUIRE, __HIP_MEMORY_SCOPE_AGENT) == g)
                __builtin_amdgcn_s_sleep(1);
        }
        __threadfence();  // acquire: inv — drop stale L1/L2 lines
    }
    __syncthreads();
}

// ---- build row-major fp8 K (padded, zeros outside real range) + init control/u ----
__global__ __launch_bounds__(256) void build_rm(const float* __restrict__ M,
                                                uint32* __restrict__ Krm,
                                                float* __restrict__ u_g,
                                                uint32* __restrict__ ctrl,
                                                float* __restrict__ err2,
                                                float* __restrict__ loss) {
    if (blockIdx.x == 0) {
        int t = threadIdx.x;
        if (t == 0) { ctrl[0] = 0u; ctrl[32] = 0u; err2[0] = 0.f; err2[1] = 0.f; *loss = 0.f; }
        for (int k = 0; k < 8; ++k) {
            int i = k * 256 + t;               // 0..2047
            u_g[i] = (i < ROWS_R) ? A_MARG : 0.0f;
        }
    }
    size_t total  = (size_t)ROWS_P * DWC_P;
    size_t stride = (size_t)gridDim.x * 256;
    for (size_t i = (size_t)blockIdx.x * 256 + threadIdx.x; i < total; i += stride) {
        int r  = (int)(i / DWC_P);
        int dc = (int)(i % DWC_P);
        int c  = dc * 4;
        uint32 pack = 0u;
        if (r < ROWS_R && c < COLS_R) {
            float4 m = *reinterpret_cast<const float4*>(M + (size_t)r * COLS_R + c);
            float k0 = expf(NALPHA * m.x), k1 = expf(NALPHA * m.y);
            float k2 = expf(NALPHA * m.z), k3 = expf(NALPHA * m.w);
            int lo = __builtin_amdgcn_cvt_pk_fp8_f32(k0, k1, 0, false);
            int hi = __builtin_amdgcn_cvt_pk_fp8_f32(k2, k3, lo, true);
            pack = (uint32)hi;
        }
        Krm[i] = pack;
    }
}

// ---- transpose Krm -> Kcm (col-major: Kcm[c*2048 + r] = K[r][c]), tile 64r x 256c ----
__global__ __launch_bounds__(256) void build_cm(const uint32* __restrict__ Krm,
                                                uint32* __restrict__ Kcm) {
    __shared__ unsigned char T[256][80];   // [local col][row byte], stride 80 (16-aligned)
    int tile = blockIdx.x;                 // 32 row-tiles x 80 col-tiles = 2560
    int r0 = (tile / 80) * 64;
    int c0 = (tile % 80) * 256;
    int t = threadIdx.x;
    for (int p = 0; p < 16; ++p) {
        int idx = p * 256 + t;
        int r  = idx >> 6;                 // 0..63
        int dc = idx & 63;                 // 0..63 dword-col
        uint32 w = Krm[(size_t)(r0 + r) * DWC_P + (c0 >> 2) + dc];
        int cl = dc * 4;
        T[cl + 0][r] = (unsigned char)(w & 0xff);
        T[cl + 1][r] = (unsigned char)((w >> 8) & 0xff);
        T[cl + 2][r] = (unsigned char)((w >> 16) & 0xff);
        T[cl + 3][r] = (unsigned char)((w >> 24) & 0xff);
    }
    __syncthreads();
    int c = t;                             // 0..255: one output column each (64 B = 16 dwords)
    const uint32* src = reinterpret_cast<const uint32*>(&T[c][0]);
    uint32* dst = Kcm + ((size_t)(c0 + c) * ROWS_P + r0) / 4;
#pragma unroll
    for (int q = 0; q < 16; ++q) dst[q] = src[q];
}

// ---- the persistent Sinkhorn loop + loss ----
__global__ __launch_bounds__(NTHR, 4) void sinkhorn_persistent(
    const float*  __restrict__ M,
    const uint32* __restrict__ Krm,
    const uint32* __restrict__ Kcm,
    float* __restrict__ u_g,
    float* __restrict__ v_g,
    float* __restrict__ vden2,
    uint32* __restrict__ ctrl,
    float* __restrict__ err2,
    float* __restrict__ loss,
    float* __restrict__ out) {
    __shared__ float s_u[ROWS_P];     // 8 KB
    __shared__ float s_v[COLS_P];     // 80 KB
    __shared__ float s_red[NWAVE];
    __shared__ int   s_flag;

    const int tid  = threadIdx.x;
    const int lane = tid & 63;
    const int wav  = tid >> 6;
    const int b    = blockIdx.x;
    uint32* cnt = ctrl;
    uint32* gen = ctrl + 32;

    const float4* s_u4 = reinterpret_cast<const float4*>(s_u);

    for (int t = 1; t <= 100; ++t) {
        // ---- stage u -> LDS ----
        s_u[tid]        = u_g[tid];
        s_u[tid + 1024] = u_g[tid + 1024];
        __syncthreads();

        // ---- column pass: v_j = b / (Kcm^T u + eps); 5 cols per wave, coalesced ----
        for (int q = 0; q < 5; ++q) {
            int j = b * 80 + wav * 5 + q;
            const uint32* colp = Kcm + (size_t)j * DWR_P;
            float acc = 0.f;
#pragma unroll
            for (int s = 0; s < 8; ++s) {
                uint32 kw = colp[s * 64 + lane];
                floatx2 f01 = __builtin_amdgcn_cvt_pk_f32_fp8(kw, false);
                floatx2 f23 = __builtin_amdgcn_cvt_pk_f32_fp8(kw, true);
                float4 uu = s_u4[s * 64 + lane];
                acc += f01.x * uu.x + f01.y * uu.y + f23.x * uu.z + f23.y * uu.w;
            }
#pragma unroll
            for (int o = 32; o; o >>= 1) acc += __shfl_xor(acc, o, 64);
            if (lane == 0) v_g[j] = B_MARG / (acc + EPSV);
        }
        grid_barrier(cnt, gen);

        // ---- stage v -> LDS ----
        {
            float4* d = reinterpret_cast<float4*>(s_v);
            const float4* srcv = reinterpret_cast<const float4*>(v_g);
#pragma unroll
            for (int k = 0; k < 5; ++k) d[k * 1024 + tid] = srcv[k * 1024 + tid];
        }
        __syncthreads();

        // ---- row pass: u_i = a / (Krm v + eps); 2 waves/row, 8 rows/block ----
        {
            int row = b * 8 + (wav >> 1);
            int h   = wav & 1;
            if (row < ROWS_R) {
                const uint32* rowp = Krm + (size_t)row * DWC_P + h * 2560;
                const float4* sv4  = reinterpret_cast<const float4*>(s_v) + h * 2560;
                float acc = 0.f;
#pragma unroll 4
                for (int s = 0; s < 40; ++s) {
                    uint32 kw = rowp[s * 64 + lane];
                    floatx2 f01 = __builtin_amdgcn_cvt_pk_f32_fp8(kw, false);
                    floatx2 f23 = __builtin_amdgcn_cvt_pk_f32_fp8(kw, true);
                    float4 vv = sv4[s * 64 + lane];
                    acc += f01.x * vv.x + f01.y * vv.y + f23.x * vv.z + f23.y * vv.w;
                }
#pragma unroll
                for (int o = 32; o; o >>= 1) acc += __shfl_xor(acc, o, 64);
                if (lane == 0) s_red[wav] = acc;
            }
        }
        __syncthreads();
        if (tid < 8) {
            int r2 = b * 8 + tid;
            if (r2 < ROWS_R) u_g[r2] = A_MARG / (s_red[2 * tid] + s_red[2 * tid + 1] + EPSV);
        }
        grid_barrier(cnt, gen);

        // ---- convergence check (reference: err updated when cpt % 50 == 1) ----
        if (t == 1 || t == 51) {
            int slot = (t == 51) ? 1 : 0;
            s_u[tid]        = u_g[tid];      // stage NEW u
            s_u[tid + 1024] = u_g[tid + 1024];
            __syncthreads();
            for (int q = 0; q < 5; ++q) {    // raw K^T u into vden2
                int j = b * 80 + wav * 5 + q;
                const uint32* colp = Kcm + (size_t)j * DWR_P;
                float acc = 0.f;
#pragma unroll
                for (int s = 0; s < 8; ++s) {
                    uint32 kw = colp[s * 64 + lane];
                    floatx2 f01 = __builtin_amdgcn_cvt_pk_f32_fp8(kw, false);
                    floatx2 f23 = __builtin_amdgcn_cvt_pk_f32_fp8(kw, true);
                    float4 uu = s_u4[s * 64 + lane];
                    acc += f01.x * uu.x + f01.y * uu.y + f23.x * uu.z + f23.y * uu.w;
                }
#pragma unroll
                for (int o = 32; o; o >>= 1) acc += __shfl_xor(acc, o, 64);
                if (lane == 0) vden2[j] = acc;
            }
            grid_barrier(cnt, gen);
            // err = sum_j |v_j * (K^T u)_j - b|
            float local = 0.f;
            int j = b * 1024 + tid;
            if (j < COLS_R) local = fabsf(s_v[j] * vden2[j] - B_MARG);
#pragma unroll
            for (int o = 32; o; o >>= 1) local += __shfl_xor(local, o, 64);
            if (lane == 0) s_red[wav] = local;
            __syncthreads();
            if (tid == 0) {
                float s = 0.f;
                for (int k = 0; k < NWAVE; ++k) s += s_red[k];
                if (s != 0.f) atomicAdd(&err2[slot], s);
            }
            grid_barrier(cnt, gen);
            if (tid == 0) s_flag = (err2[slot] <= THR) ? 1 : 0;
            __syncthreads();
            if (s_flag) break;               // uniform across the grid
        }
    }

    // ---- loss = sum_ij u_i exp(-20 M_ij) v_j M_ij  (fp32 K from M; s_v holds final v) ----
    {
        const float4* sv4 = reinterpret_cast<const float4*>(s_v);
        int rw = b * NWAVE + wav;            // 4096 waves >= 2000 rows
        if (rw < ROWS_R) {
            const float4* mrow = reinterpret_cast<const float4*>(M + (size_t)rw * COLS_R);
            float acc = 0.f;
            for (int s = 0; s < 79; ++s) {
                int ci = s * 64 + lane;
                if (ci < 5000) {
                    float4 m = mrow[ci];
                    float4 vv = sv4[ci];
                    acc += expf(NALPHA * m.x) * vv.x * m.x;
                    acc += expf(NALPHA * m.y) * vv.y * m.y;
                    acc += expf(NALPHA * m.z) * vv.z * m.z;
                    acc += expf(NALPHA * m.w) * vv.w * m.w;
                }
            }
#pragma unroll
            for (int o = 32; o; o >>= 1) acc += __shfl_xor(acc, o, 64);
            if (lane == 0) atomicAdd(loss, acc * u_g[rw]);
        }
    }
    grid_barrier(cnt, gen);
    if (b == 0 && tid == 0) out[0] = *loss * 100.0f;
}

// ============================ fallback path (tiny workspace) ============================

__device__ __forceinline__ float block_reduce_sum256(float v) {
#pragma unroll
    for (int o = 32; o; o >>= 1) v += __shfl_down(v, o, 64);
    __shared__ float smem[4];
    int lane = threadIdx.x & 63, w = threadIdx.x >> 6;
    if (lane == 0) smem[w] = v;
    __syncthreads();
    v = (threadIdx.x < 4) ? smem[threadIdx.x] : 0.0f;
    v += __shfl_down(v, 2, 64);
    v += __shfl_down(v, 1, 64);
    return v;
}

__global__ __launch_bounds__(256) void fb_init(float* u, float* vden, int* done, float* err, float* loss) {
    int idx = blockIdx.x * 256 + threadIdx.x;
    if (idx == 0) { *done = 0; *err = 0.0f; *loss = 0.0f; }
    if (idx < ROWS_R) u[idx] = A_MARG;
    if (idx < COLS_R) vden[idx] = 0.0f;
}
__global__ __launch_bounds__(256) void fb_colpass(const float* __restrict__ M, const float* __restrict__ u,
                                                  float* __restrict__ vden, const int* __restrict__ done) {
    if (*done) return;
    int c4 = blockIdx.x * 256 + threadIdx.x;
    if (c4 >= 5000) return;
    int r0 = blockIdx.y * 50;
    float4 acc = make_float4(0.f, 0.f, 0.f, 0.f);
    for (int r = r0; r < r0 + 50; ++r) {
        float ui = u[r];
        float4 mm = reinterpret_cast<const float4*>(M)[(size_t)r * 5000 + c4];
        acc.x += expf(NALPHA * mm.x) * ui; acc.y += expf(NALPHA * mm.y) * ui;
        acc.z += expf(NALPHA * mm.z) * ui; acc.w += expf(NALPHA * mm.w) * ui;
    }
    atomicAdd(&vden[c4 * 4 + 0], acc.x); atomicAdd(&vden[c4 * 4 + 1], acc.y);
    atomicAdd(&vden[c4 * 4 + 2], acc.z); atomicAdd(&vden[c4 * 4 + 3], acc.w);
}
__global__ __launch_bounds__(256) void fb_finv(float* v, float* vden, const int* done) {
    if (*done) return;
    int j = blockIdx.x * 256 + threadIdx.x;
    if (j < COLS_R) { v[j] = B_MARG / (vden[j] + EPSV); vden[j] = 0.0f; }
}
__global__ __launch_bounds__(256) void fb_rowpass(const float* __restrict__ M, const float* __restrict__ v,
                                                  float* __restrict__ u, const int* __restrict__ done) {
    if (*done) return;
    int row = blockIdx.x;
    const float4* v4 = reinterpret_cast<const float4*>(v);
    float acc = 0.0f;
    for (int c4 = threadIdx.x; c4 < 5000; c4 += 256) {
        float4 mm = reinterpret_cast<const float4*>(M)[(size_t)row * 5000 + c4];
        float4 vv = v4[c4];
        acc += expf(NALPHA * mm.x) * vv.x + expf(NALPHA * mm.y) * vv.y
             + expf(NALPHA * mm.z) * vv.z + expf(NALPHA * mm.w) * vv.w;
    }
    float s = block_reduce_sum256(acc);
    if (threadIdx.x == 0) u[row] = A_MARG / (s + EPSV);
}
__global__ __launch_bounds__(256) void fb_errfin(const float* v, float* vden, float* err, const int* done) {
    if (*done) return;
    int j = blockIdx.x * 256 + threadIdx.x;
    float local = 0.0f;
    if (j < COLS_R) { local = fabsf(v[j] * vden[j] - B_MARG); vden[j] = 0.0f; }
    float s = block_reduce_sum256(local);
    if (threadIdx.x == 0) atomicAdd(err, s);
}
__global__ void fb_check(int* done, float* err) {
    if (threadIdx.x == 0) { if (!*done && *err <= THR) *done = 1; *err = 0.0f; }
}
__global__ __launch_bounds__(256) void fb_loss(const float* __restrict__ M, const float* __restrict__ u,
                                               const float* __restrict__ v, float* __restrict__ loss) {
    int row = blockIdx.x;
    const float4* M4p = reinterpret_cast<const float4*>(M + (size_t)row * COLS_R);
    const float4* v4 = reinterpret_cast<const float4*>(v);
    float acc = 0.0f;
    for (int c4 = threadIdx.x; c4 < 5000; c4 += 256) {
        float4 mm = M4p[c4]; float4 vv = v4[c4];
        acc += expf(NALPHA * mm.x) * vv.x * mm.x + expf(NALPHA * mm.y) * vv.y * mm.y
             + expf(NALPHA * mm.z) * vv.z * mm.z + expf(NALPHA * mm.w) * vv.w * mm.w;
    }
    float s = block_reduce_sum256(acc);
    if (threadIdx.x == 0) atomicAdd(loss, s * u[row]);
}
__global__ void fb_writeout(float* out, const float* loss) {
    if (threadIdx.x == 0) out[0] = *loss * 100.0f;
}

// ============================ host launch ============================

extern "C" void kernel_launch(void* const* d_in, const int* in_sizes, int n_in,
                              void* d_out, int out_size, void* d_ws, size_t ws_size,
                              hipStream_t stream) {
    const float* M = (const float*)d_in[0];
    char* base = (char*)d_ws;

    // persistent-path workspace layout
    const size_t OFF_CTRL = 0;                       // uint32[64] (cnt @0, gen @128B)
    const size_t OFF_ERR  = 256;
    const size_t OFF_LOSS = 384;
    const size_t OFF_U    = 512;                     // 2048 f
    const size_t OFF_V    = OFF_U + 8192;            // 20480 f
    const size_t OFF_VD2  = OFF_V + 81920;           // 20480 f
    const size_t OFF_KRM  = OFF_VD2 + 81920;         // 172544, 256-aligned
    const size_t K_BYTES  = (size_t)ROWS_P * COLS_P; // 41.94 MB
    const size_t OFF_KCM  = OFF_KRM + K_BYTES;
    const size_t NEED     = OFF_KCM + K_BYTES;       // ~84.06 MB

    if (ws_size >= NEED) {
        uint32* ctrl  = (uint32*)(base + OFF_CTRL);
        float*  err2  = (float*)(base + OFF_ERR);
        float*  loss  = (float*)(base + OFF_LOSS);
        float*  u_g   = (float*)(base + OFF_U);
        float*  v_g   = (float*)(base + OFF_V);
        float*  vden2 = (float*)(base + OFF_VD2);
        uint32* Krm   = (uint32*)(base + OFF_KRM);
        uint32* Kcm   = (uint32*)(base + OFF_KCM);

        build_rm<<<4096, 256, 0, stream>>>(M, Krm, u_g, ctrl, err2, loss);
        build_cm<<<2560, 256, 0, stream>>>(Krm, Kcm);
        sinkhorn_persistent<<<NBLK, NTHR, 0, stream>>>(M, Krm, Kcm, u_g, v_g, vden2,
                                                       ctrl, err2, loss, (float*)d_out);
    } else {
        // tiny-workspace fallback: round-1 multi-kernel pipeline, exp recomputed from M
        int*   done = (int*)(base + 0);
        float* err  = (float*)(base + 8);
        float* loss = (float*)(base + 16);
        float* u    = (float*)(base + 64);
        float* v    = (float*)(base + 64 + 8192);
        float* vden = (float*)(base + 64 + 8192 + 80000);

        fb_init<<<79, 256, 0, stream>>>(u, vden, done, err, loss);
        dim3 cgrid(20, 40);
        for (int t = 1; t <= 100; ++t) {
            fb_colpass<<<cgrid, 256, 0, stream>>>(M, u, vden, done);
            fb_finv<<<79, 256, 0, stream>>>(v, vden, done);
            fb_rowpass<<<ROWS_R, 256, 0, stream>>>(M, v, u, done);
            if (t == 1 || t == 51) {
                fb_colpass<<<cgrid, 256, 0, stream>>>(M, u, vden, done);
                fb_errfin<<<79, 256, 0, stream>>>(v, vden, err, done);
                fb_check<<<1, 64, 0, stream>>>(done, err);
            }
        }
        fb_loss<<<ROWS_R, 256, 0, stream>>>(M, u, v, loss);
        fb_writeout<<<1, 64, 0, stream>>>((float*)d_out, loss);
    }
}

// Round 3
// 468.975 us; speedup vs baseline: 1.7245x; 1.1190x over previous
//
#include <hip/hip_runtime.h>
#include <hip/hip_fp16.h>

typedef unsigned int uint32;
typedef float floatx2 __attribute__((ext_vector_type(2)));

#define ROWS_R 2000
#define COLS_R 20000
#define ROWS_P 2048
#define COLS_P 20480
#define DWC_P  (COLS_P/4)   /* 5120 fp8-dwords per padded row */
#define DWR_P  (ROWS_P/4)   /* 512 fp8-dwords per padded col  */
#define NBLK   256
#define NTHR   1024
#define NWAVE  16

static constexpr float A_MARG = 1.0f / 2000.0f;
static constexpr float B_MARG = 1.0f / 20000.0f;
static constexpr float EPSV   = 1e-16f;
static constexpr float THR    = 0.005f;
static constexpr float NALPHA = -20.0f;

// ======================= two-level grid barrier (persistent path) =======================
// ctrl dwords: [0]=root_cnt, [64]=root_gen, [128+g*64]=group_cnt, [768+g*64]=group_gen.
// Monotonic counters (never reset) -> no reset races. Relaxed polls + one acquire fence.
__device__ __forceinline__ void grid_barrier(uint32* ctrl, uint32 rnd) {
    __syncthreads();
    if (threadIdx.x == 0) {
        const int gid = (int)(blockIdx.x >> 5);
        uint32* gcnt = ctrl + 128 + gid * 64;
        uint32* ggen = ctrl + 768 + gid * 64;
        __threadfence();  // release: publish this block's data
        uint32 a = __hip_atomic_fetch_add(gcnt, 1u, __ATOMIC_RELAXED, __HIP_MEMORY_SCOPE_AGENT);
        if (a == rnd * 32u + 31u) {            // last in group -> go to root
            uint32 r = __hip_atomic_fetch_add(ctrl, 1u, __ATOMIC_RELAXED, __HIP_MEMORY_SCOPE_AGENT);
            if (r == rnd * 8u + 7u) {          // last group -> release root
                __hip_atomic_fetch_add(ctrl + 64, 1u, __ATOMIC_RELAXED, __HIP_MEMORY_SCOPE_AGENT);
            } else {
                while (__hip_atomic_load(ctrl + 64, __ATOMIC_RELAXED, __HIP_MEMORY_SCOPE_AGENT) < rnd + 1u)
                    __builtin_amdgcn_s_sleep(1);
            }
            __hip_atomic_fetch_add(ggen, 1u, __ATOMIC_RELAXED, __HIP_MEMORY_SCOPE_AGENT);
        } else {
            while (__hip_atomic_load(ggen, __ATOMIC_RELAXED, __HIP_MEMORY_SCOPE_AGENT) < rnd + 1u)
                __builtin_amdgcn_s_sleep(1);
        }
        __threadfence();  // acquire: drop stale lines
    }
    __syncthreads();
}

// ======================= fused build: M -> Krm (fp8) + Kcm (fp8 transposed) =======================
// grid 2560 = 32 row-tiles x 80 col-tiles; tile = 64 rows x 256 cols. 256 threads.
// Thread handles a 4x4 micro-tile: reads 4 float4 of M, makes 4 packed-fp8 dwords (rows),
// writes Krm coalesced, transposes 4x4 bytes in registers (v_perm) and stages columns in LDS.
__global__ __launch_bounds__(256) void build_fused(const float* __restrict__ M,
                                                   uint32* __restrict__ Krm,
                                                   uint32* __restrict__ Kcm,
                                                   float* __restrict__ u_g,
                                                   uint32* __restrict__ ctrl,
                                                   float* __restrict__ err2,
                                                   float* __restrict__ loss) {
    __shared__ uint32 T[256 * 17];   // T[c*17 + rb]: dword = rows 4rb..4rb+3 of local col c

    if (blockIdx.x == 0) {           // init control state (ws is poisoned each launch)
        int t = threadIdx.x;
        for (int k = t; k < 1280; k += 256) ctrl[k] = 0u;
        if (t == 0) { err2[0] = 0.f; err2[1] = 0.f; *loss = 0.f; }
        for (int k = 0; k < 8; ++k) {
            int i = k * 256 + t;
            u_g[i] = (i < ROWS_R) ? A_MARG : 0.0f;
        }
    }

    const int rt = blockIdx.x / 80;
    const int ct = blockIdx.x % 80;
    const int r0 = rt * 64;
    const int c0 = ct * 256;
    const int t  = threadIdx.x;
    const int dc = t & 63;           // float4-column within tile (0..63)
    const int w  = t >> 6;

    for (int p = 0; p < 4; ++p) {
        const int rb  = p * 4 + w;   // row-quad index (0..15)
        const int col = c0 + dc * 4;
        uint32 kd[4];
#pragma unroll
        for (int i = 0; i < 4; ++i) {
            const int r = r0 + rb * 4 + i;
            uint32 pack = 0u;
            if (r < ROWS_R && col < COLS_R) {
                float4 m = *reinterpret_cast<const float4*>(M + (size_t)r * COLS_R + col);
                float k0 = __expf(NALPHA * m.x), k1 = __expf(NALPHA * m.y);
                float k2 = __expf(NALPHA * m.z), k3 = __expf(NALPHA * m.w);
                int lo = __builtin_amdgcn_cvt_pk_fp8_f32(k0, k1, 0, false);
                int hi = __builtin_amdgcn_cvt_pk_fp8_f32(k2, k3, lo, true);
                pack = (uint32)hi;
            }
            kd[i] = pack;
            Krm[(size_t)(r0 + rb * 4 + i) * DWC_P + (c0 >> 2) + dc] = pack;
        }
        // 4x4 byte transpose in registers
        uint32 x0 = __builtin_amdgcn_perm(kd[1], kd[0], 0x05010400u); // [k0b0,k1b0,k0b1,k1b1]
        uint32 x1 = __builtin_amdgcn_perm(kd[1], kd[0], 0x07030602u); // [k0b2,k1b2,k0b3,k1b3]
        uint32 x2 = __builtin_amdgcn_perm(kd[3], kd[2], 0x05010400u);
        uint32 x3 = __builtin_amdgcn_perm(kd[3], kd[2], 0x07030602u);
        uint32 o0 = __builtin_amdgcn_perm(x2, x0, 0x05040100u);       // col 4dc+0, rows 0..3
        uint32 o1 = __builtin_amdgcn_perm(x2, x0, 0x07060302u);
        uint32 o2 = __builtin_amdgcn_perm(x3, x1, 0x05040100u);
        uint32 o3 = __builtin_amdgcn_perm(x3, x1, 0x07060302u);
        T[(4 * dc + 0) * 17 + rb] = o0;
        T[(4 * dc + 1) * 17 + rb] = o1;
        T[(4 * dc + 2) * 17 + rb] = o2;
        T[(4 * dc + 3) * 17 + rb] = o3;
    }
    __syncthreads();

    // phase 2: thread c owns output column c0+c -> 16 dwords = rows r0..r0+63
    {
        const int c = t;
        uint32* dst = Kcm + (size_t)(c0 + c) * DWR_P + (r0 >> 2);
#pragma unroll
        for (int m4 = 0; m4 < 4; ++m4) {
            uint32 d0 = T[c * 17 + 4 * m4 + 0];
            uint32 d1 = T[c * 17 + 4 * m4 + 1];
            uint32 d2 = T[c * 17 + 4 * m4 + 2];
            uint32 d3 = T[c * 17 + 4 * m4 + 3];
            uint4 vv = make_uint4(d0, d1, d2, d3);
            *reinterpret_cast<uint4*>(dst + 4 * m4) = vv;
        }
    }
}

// ======================= persistent Sinkhorn loop + loss =======================
__global__ __launch_bounds__(NTHR, 4) void sinkhorn_persistent(
    const float*  __restrict__ M,
    const uint32* __restrict__ Krm,
    const uint32* __restrict__ Kcm,
    float* __restrict__ u_g,
    float* __restrict__ v_g,
    float* __restrict__ vden2,
    uint32* __restrict__ ctrl,
    float* __restrict__ err2,
    float* __restrict__ loss,
    float* __restrict__ out) {
    __shared__ float s_v[COLS_P];          // 80 KB
    __shared__ float s_red[NWAVE * 4];
    __shared__ int   s_flag;

    const int tid  = threadIdx.x;
    const int lane = tid & 63;
    const int wav  = tid >> 6;
    const int b    = blockIdx.x;
    uint32 bar = 0;

    const float4* u_g4 = reinterpret_cast<const float4*>(u_g);

    for (int t = 1; t <= 100; ++t) {
        // ---- load u into registers: lane owns u[4*(s*64+lane) .. +3] for s=0..7 ----
        float4 u_r[8];
#pragma unroll
        for (int s = 0; s < 8; ++s) u_r[s] = u_g4[s * 64 + lane];

        // ---- column pass: v_j = b / (K^T u + eps); 5 cols/wave, zero LDS ----
#pragma unroll
        for (int q = 0; q < 5; ++q) {
            const int j = b * 80 + wav * 5 + q;
            const uint32* colp = Kcm + (size_t)j * DWR_P;
            float acc = 0.f;
#pragma unroll
            for (int s = 0; s < 8; ++s) {
                uint32 kw = colp[s * 64 + lane];
                floatx2 f01 = __builtin_amdgcn_cvt_pk_f32_fp8(kw, false);
                floatx2 f23 = __builtin_amdgcn_cvt_pk_f32_fp8(kw, true);
                acc += f01.x * u_r[s].x + f01.y * u_r[s].y + f23.x * u_r[s].z + f23.y * u_r[s].w;
            }
#pragma unroll
            for (int o = 32; o; o >>= 1) acc += __shfl_xor(acc, o, 64);
            if (lane == 0) v_g[j] = B_MARG / (acc + EPSV);
        }
        grid_barrier(ctrl, bar++);

        // ---- stage v -> LDS (only consumer: row pass, 4 rows per v-read) ----
        {
            float4* d = reinterpret_cast<float4*>(s_v);
            const float4* srcv = reinterpret_cast<const float4*>(v_g);
#pragma unroll
            for (int k = 0; k < 5; ++k) d[k * 1024 + tid] = srcv[k * 1024 + tid];
        }
        __syncthreads();

        // ---- row pass: wave = (row-quad rq, col-segment sg); 4 rows x 1/8 width ----
        {
            const int rq = wav >> 3;           // 0..1
            const int sg = wav & 7;            // 0..7
            const int rbase = b * 8 + rq * 4;
            const uint32* kp  = Krm + (size_t)rbase * DWC_P + sg * 640;
            const float4* sv4 = reinterpret_cast<const float4*>(s_v) + sg * 640;
            float acc0 = 0.f, acc1 = 0.f, acc2 = 0.f, acc3 = 0.f;
#pragma unroll 2
            for (int s = 0; s < 10; ++s) {
                const int idx = s * 64 + lane;
                float4 vv = sv4[idx];
                uint32 k0 = kp[idx];
                uint32 k1 = kp[idx + DWC_P];
                uint32 k2 = kp[idx + 2 * DWC_P];
                uint32 k3 = kp[idx + 3 * DWC_P];
                floatx2 a0 = __builtin_amdgcn_cvt_pk_f32_fp8(k0, false);
                floatx2 b0 = __builtin_amdgcn_cvt_pk_f32_fp8(k0, true);
                acc0 += a0.x * vv.x + a0.y * vv.y + b0.x * vv.z + b0.y * vv.w;
                floatx2 a1 = __builtin_amdgcn_cvt_pk_f32_fp8(k1, false);
                floatx2 b1 = __builtin_amdgcn_cvt_pk_f32_fp8(k1, true);
                acc1 += a1.x * vv.x + a1.y * vv.y + b1.x * vv.z + b1.y * vv.w;
                floatx2 a2 = __builtin_amdgcn_cvt_pk_f32_fp8(k2, false);
                floatx2 b2 = __builtin_amdgcn_cvt_pk_f32_fp8(k2, true);
                acc2 += a2.x * vv.x + a2.y * vv.y + b2.x * vv.z + b2.y * vv.w;
                floatx2 a3 = __builtin_amdgcn_cvt_pk_f32_fp8(k3, false);
                floatx2 b3 = __builtin_amdgcn_cvt_pk_f32_fp8(k3, true);
                acc3 += a3.x * vv.x + a3.y * vv.y + b3.x * vv.z + b3.y * vv.w;
            }
#pragma unroll
            for (int o = 32; o; o >>= 1) {
                acc0 += __shfl_xor(acc0, o, 64);
                acc1 += __shfl_xor(acc1, o, 64);
                acc2 += __shfl_xor(acc2, o, 64);
                acc3 += __shfl_xor(acc3, o, 64);
            }
            if (lane == 0) {
                s_red[wav * 4 + 0] = acc0;
                s_red[wav * 4 + 1] = acc1;
                s_red[wav * 4 + 2] = acc2;
                s_red[wav * 4 + 3] = acc3;
            }
        }
        __syncthreads();
        if (tid < 8) {
            const int row = b * 8 + tid;
            if (row < ROWS_R) {
                const int rq2 = tid >> 2, i = tid & 3;
                float s = 0.f;
#pragma unroll
                for (int sg = 0; sg < 8; ++sg) s += s_red[(rq2 * 8 + sg) * 4 + i];
                u_g[row] = A_MARG / (s + EPSV);
            }
        }
        grid_barrier(ctrl, bar++);

        // ---- convergence check (reference updates err only at cpt=1,51) ----
        if (t == 1 || t == 51) {
            const int slot = (t == 51) ? 1 : 0;
            float4 un_r[8];
#pragma unroll
            for (int s = 0; s < 8; ++s) un_r[s] = u_g4[s * 64 + lane];   // NEW u
#pragma unroll
            for (int q = 0; q < 5; ++q) {
                const int j = b * 80 + wav * 5 + q;
                const uint32* colp = Kcm + (size_t)j * DWR_P;
                float acc = 0.f;
#pragma unroll
                for (int s = 0; s < 8; ++s) {
                    uint32 kw = colp[s * 64 + lane];
                    floatx2 f01 = __builtin_amdgcn_cvt_pk_f32_fp8(kw, false);
                    floatx2 f23 = __builtin_amdgcn_cvt_pk_f32_fp8(kw, true);
                    acc += f01.x * un_r[s].x + f01.y * un_r[s].y + f23.x * un_r[s].z + f23.y * un_r[s].w;
                }
#pragma unroll
                for (int o = 32; o; o >>= 1) acc += __shfl_xor(acc, o, 64);
                if (lane == 0) vden2[j] = acc;
            }
            grid_barrier(ctrl, bar++);
            // err = sum_j |v_j * (K^T u)_j - b| ; only blocks 0..19 hold real j
            float local = 0.f;
            const int j = b * 1024 + tid;
            if (j < COLS_R) local = fabsf(s_v[j] * vden2[j] - B_MARG);
#pragma unroll
            for (int o = 32; o; o >>= 1) local += __shfl_xor(local, o, 64);
            if (lane == 0) s_red[wav] = local;
            __syncthreads();
            if (tid == 0) {
                float s = 0.f;
                for (int k = 0; k < NWAVE; ++k) s += s_red[k];
                if (s != 0.f) atomicAdd(&err2[slot], s);
            }
            grid_barrier(ctrl, bar++);
            if (tid == 0) s_flag = (err2[slot] <= THR) ? 1 : 0;
            __syncthreads();
            if (s_flag) break;   // uniform across grid
        }
    }

    // ---- loss = sum_ij u_i exp(-20 M_ij) v_j M_ij (fp32 from M; s_v holds final v) ----
    {
        const float4* sv4 = reinterpret_cast<const float4*>(s_v);
        const int rw = b * NWAVE + wav;       // 4096 waves >= 2000 rows
        if (rw < ROWS_R) {
            const float4* mrow = reinterpret_cast<const float4*>(M + (size_t)rw * COLS_R);
            float acc = 0.f;
            for (int ci = lane; ci < 5000; ci += 64) {
                float4 m = mrow[ci];
                float4 vv = sv4[ci];
                acc += __expf(NALPHA * m.x) * vv.x * m.x;
                acc += __expf(NALPHA * m.y) * vv.y * m.y;
                acc += __expf(NALPHA * m.z) * vv.z * m.z;
                acc += __expf(NALPHA * m.w) * vv.w * m.w;
            }
#pragma unroll
            for (int o = 32; o; o >>= 1) acc += __shfl_xor(acc, o, 64);
            if (lane == 0) atomicAdd(loss, acc * u_g[rw]);
        }
    }
    grid_barrier(ctrl, bar++);
    if (b == 0 && tid == 0) out[0] = *loss * 100.0f;
}

// ======================= fallback path (tiny workspace) =======================

__device__ __forceinline__ float block_reduce_sum256(float v) {
#pragma unroll
    for (int o = 32; o; o >>= 1) v += __shfl_down(v, o, 64);
    __shared__ float smem[4];
    int lane = threadIdx.x & 63, w = threadIdx.x >> 6;
    if (lane == 0) smem[w] = v;
    __syncthreads();
    v = (threadIdx.x < 4) ? smem[threadIdx.x] : 0.0f;
    v += __shfl_down(v, 2, 64);
    v += __shfl_down(v, 1, 64);
    return v;
}

__global__ __launch_bounds__(256) void fb_init(float* u, float* vden, int* done, float* err, float* loss) {
    int idx = blockIdx.x * 256 + threadIdx.x;
    if (idx == 0) { *done = 0; *err = 0.0f; *loss = 0.0f; }
    if (idx < ROWS_R) u[idx] = A_MARG;
    if (idx < COLS_R) vden[idx] = 0.0f;
}
__global__ __launch_bounds__(256) void fb_colpass(const float* __restrict__ M, const float* __restrict__ u,
                                                  float* __restrict__ vden, const int* __restrict__ done) {
    if (*done) return;
    int c4 = blockIdx.x * 256 + threadIdx.x;
    if (c4 >= 5000) return;
    int r0 = blockIdx.y * 50;
    float4 acc = make_float4(0.f, 0.f, 0.f, 0.f);
    for (int r = r0; r < r0 + 50; ++r) {
        float ui = u[r];
        float4 mm = reinterpret_cast<const float4*>(M)[(size_t)r * 5000 + c4];
        acc.x += __expf(NALPHA * mm.x) * ui; acc.y += __expf(NALPHA * mm.y) * ui;
        acc.z += __expf(NALPHA * mm.z) * ui; acc.w += __expf(NALPHA * mm.w) * ui;
    }
    atomicAdd(&vden[c4 * 4 + 0], acc.x); atomicAdd(&vden[c4 * 4 + 1], acc.y);
    atomicAdd(&vden[c4 * 4 + 2], acc.z); atomicAdd(&vden[c4 * 4 + 3], acc.w);
}
__global__ __launch_bounds__(256) void fb_finv(float* v, float* vden, const int* done) {
    if (*done) return;
    int j = blockIdx.x * 256 + threadIdx.x;
    if (j < COLS_R) { v[j] = B_MARG / (vden[j] + EPSV); vden[j] = 0.0f; }
}
__global__ __launch_bounds__(256) void fb_rowpass(const float* __restrict__ M, const float* __restrict__ v,
                                                  float* __restrict__ u, const int* __restrict__ done) {
    if (*done) return;
    int row = blockIdx.x;
    const float4* v4 = reinterpret_cast<const float4*>(v);
    float acc = 0.0f;
    for (int c4 = threadIdx.x; c4 < 5000; c4 += 256) {
        float4 mm = reinterpret_cast<const float4*>(M)[(size_t)row * 5000 + c4];
        float4 vv = v4[c4];
        acc += __expf(NALPHA * mm.x) * vv.x + __expf(NALPHA * mm.y) * vv.y
             + __expf(NALPHA * mm.z) * vv.z + __expf(NALPHA * mm.w) * vv.w;
    }
    float s = block_reduce_sum256(acc);
    if (threadIdx.x == 0) u[row] = A_MARG / (s + EPSV);
}
__global__ __launch_bounds__(256) void fb_errfin(const float* v, float* vden, float* err, const int* done) {
    if (*done) return;
    int j = blockIdx.x * 256 + threadIdx.x;
    float local = 0.0f;
    if (j < COLS_R) { local = fabsf(v[j] * vden[j] - B_MARG); vden[j] = 0.0f; }
    float s = block_reduce_sum256(local);
    if (threadIdx.x == 0) atomicAdd(err, s);
}
__global__ void fb_check(int* done, float* err) {
    if (threadIdx.x == 0) { if (!*done && *err <= THR) *done = 1; *err = 0.0f; }
}
__global__ __launch_bounds__(256) void fb_loss(const float* __restrict__ M, const float* __restrict__ u,
                                               const float* __restrict__ v, float* __restrict__ loss) {
    int row = blockIdx.x;
    const float4* M4p = reinterpret_cast<const float4*>(M + (size_t)row * COLS_R);
    const float4* v4 = reinterpret_cast<const float4*>(v);
    float acc = 0.0f;
    for (int c4 = threadIdx.x; c4 < 5000; c4 += 256) {
        float4 mm = M4p[c4]; float4 vv = v4[c4];
        acc += __expf(NALPHA * mm.x) * vv.x * mm.x + __expf(NALPHA * mm.y) * vv.y * mm.y
             + __expf(NALPHA * mm.z) * vv.z * mm.z + __expf(NALPHA * mm.w) * vv.w * mm.w;
    }
    float s = block_reduce_sum256(acc);
    if (threadIdx.x == 0) atomicAdd(loss, s * u[row]);
}
__global__ void fb_writeout(float* out, const float* loss) {
    if (threadIdx.x == 0) out[0] = *loss * 100.0f;
}

// ======================= host launch =======================

extern "C" void kernel_launch(void* const* d_in, const int* in_sizes, int n_in,
                              void* d_out, int out_size, void* d_ws, size_t ws_size,
                              hipStream_t stream) {
    const float* M = (const float*)d_in[0];
    char* base = (char*)d_ws;

    const size_t OFF_CTRL = 0;                        // uint32[2048] (8 KB; 1280 used)
    const size_t OFF_ERR  = 8192;
    const size_t OFF_LOSS = 8320;
    const size_t OFF_U    = 8448;                     // 2048 f
    const size_t OFF_V    = OFF_U + 8192;             // 20480 f
    const size_t OFF_VD2  = OFF_V + 81920;            // 20480 f
    const size_t OFF_KRM  = OFF_VD2 + 81920;          // 180480 (256-aligned)
    const size_t K_BYTES  = (size_t)ROWS_P * COLS_P;  // 41.94 MB
    const size_t OFF_KCM  = OFF_KRM + K_BYTES;
    const size_t NEED     = OFF_KCM + K_BYTES;        // ~84.1 MB

    if (ws_size >= NEED) {
        uint32* ctrl  = (uint32*)(base + OFF_CTRL);
        float*  err2  = (float*)(base + OFF_ERR);
        float*  loss  = (float*)(base + OFF_LOSS);
        float*  u_g   = (float*)(base + OFF_U);
        float*  v_g   = (float*)(base + OFF_V);
        float*  vden2 = (float*)(base + OFF_VD2);
        uint32* Krm   = (uint32*)(base + OFF_KRM);
        uint32* Kcm   = (uint32*)(base + OFF_KCM);

        build_fused<<<2560, 256, 0, stream>>>(M, Krm, Kcm, u_g, ctrl, err2, loss);
        sinkhorn_persistent<<<NBLK, NTHR, 0, stream>>>(M, Krm, Kcm, u_g, v_g, vden2,
                                                       ctrl, err2, loss, (float*)d_out);
    } else {
        int*   done = (int*)(base + 0);
        float* err  = (float*)(base + 8);
        float* loss = (float*)(base + 16);
        float* u    = (float*)(base + 64);
        float* v    = (float*)(base + 64 + 8192);
        float* vden = (float*)(base + 64 + 8192 + 80000);

        fb_init<<<79, 256, 0, stream>>>(u, vden, done, err, loss);
        dim3 cgrid(20, 40);
        for (int t = 1; t <= 100; ++t) {
            fb_colpass<<<cgrid, 256, 0, stream>>>(M, u, vden, done);
            fb_finv<<<79, 256, 0, stream>>>(v, vden, done);
            fb_rowpass<<<ROWS_R, 256, 0, stream>>>(M, v, u, done);
            if (t == 1 || t == 51) {
                fb_colpass<<<cgrid, 256, 0, stream>>>(M, u, vden, done);
                fb_errfin<<<79, 256, 0, stream>>>(v, vden, err, done);
                fb_check<<<1, 64, 0, stream>>>(done, err);
            }
        }
        fb_loss<<<ROWS_R, 256, 0, stream>>>(M, u, v, loss);
        fb_writeout<<<1, 64, 0, stream>>>((float*)d_out, loss);
    }
}

// Round 4
// 456.944 us; speedup vs baseline: 1.7699x; 1.0263x over previous
//
#include <hip/hip_runtime.h>
#include <hip/hip_fp16.h>

typedef unsigned int uint32;
typedef float floatx2 __attribute__((ext_vector_type(2)));

#define ROWS_R 2000
#define COLS_R 20000
#define ROWS_P 2048
#define COLS_P 20480
#define DWC_P  (COLS_P/4)   /* 5120 fp8-dwords per padded row */
#define DWR_P  (ROWS_P/4)   /* 512 fp8-dwords per padded col  */
#define NBLK   256
#define NTHR   1024
#define NWAVE  16

static constexpr float A_MARG = 1.0f / 2000.0f;
static constexpr float B_MARG = 1.0f / 20000.0f;
static constexpr float EPSV   = 1e-16f;
static constexpr float THR    = 0.005f;
static constexpr float NALPHA = -20.0f;

// ======================= two-level grid barrier =======================
// ctrl dwords: [0]=root_cnt, [64]=root_gen, [128+g*64]=group_cnt, [768+g*64]=group_gen.
// Monotonic counters; relaxed polls + fences at the edges.
__device__ __forceinline__ void grid_barrier(uint32* ctrl, uint32 rnd) {
    __syncthreads();
    if (threadIdx.x == 0) {
        const int gid = (int)(blockIdx.x >> 5);
        uint32* gcnt = ctrl + 128 + gid * 64;
        uint32* ggen = ctrl + 768 + gid * 64;
        __threadfence();
        uint32 a = __hip_atomic_fetch_add(gcnt, 1u, __ATOMIC_RELAXED, __HIP_MEMORY_SCOPE_AGENT);
        if (a == rnd * 32u + 31u) {
            uint32 r = __hip_atomic_fetch_add(ctrl, 1u, __ATOMIC_RELAXED, __HIP_MEMORY_SCOPE_AGENT);
            if (r == rnd * 8u + 7u) {
                __hip_atomic_fetch_add(ctrl + 64, 1u, __ATOMIC_RELAXED, __HIP_MEMORY_SCOPE_AGENT);
            } else {
                while (__hip_atomic_load(ctrl + 64, __ATOMIC_RELAXED, __HIP_MEMORY_SCOPE_AGENT) < rnd + 1u)
                    __builtin_amdgcn_s_sleep(1);
            }
            __hip_atomic_fetch_add(ggen, 1u, __ATOMIC_RELAXED, __HIP_MEMORY_SCOPE_AGENT);
        } else {
            while (__hip_atomic_load(ggen, __ATOMIC_RELAXED, __HIP_MEMORY_SCOPE_AGENT) < rnd + 1u)
                __builtin_amdgcn_s_sleep(1);
        }
        __threadfence();
    }
    __syncthreads();
}

// ======================= build v2: column-stripe blocks, coalesced stores =======================
// grid 1280 = 320 col-stripes (64 cols) x 4 row-chunks (512 rows). 256 threads.
// Krm stores: full 64B line segments. Kcm stores: 512B contiguous segments via LDS tile.
#define TSTRIDE 132   /* dwords per LDS column; %32=4 -> with swizzle ~4-way conflicts */
__global__ __launch_bounds__(256) void build_v2(const float* __restrict__ M,
                                                uint32* __restrict__ Krm,
                                                uint32* __restrict__ Kcm,
                                                float* __restrict__ u_g,
                                                uint32* __restrict__ ctrl,
                                                float* __restrict__ err2,
                                                float* __restrict__ loss) {
    __shared__ uint32 T[64 * TSTRIDE];   // [col 0..63][rq 0..127 swizzled], ~33.8 KB

    if (blockIdx.x == 0) {               // init control state (ws poisoned each launch)
        int t = threadIdx.x;
        for (int k = t; k < 1280; k += 256) ctrl[k] = 0u;
        if (t == 0) { err2[0] = 0.f; err2[1] = 0.f; *loss = 0.f; }
        for (int k = 0; k < 8; ++k) {
            int i = k * 256 + t;
            u_g[i] = (i < ROWS_R) ? A_MARG : 0.0f;
        }
    }

    const int c64   = blockIdx.x % 320;   // col-stripe
    const int chunk = blockIdx.x / 320;   // row-chunk (512 rows)
    const int c0    = c64 * 64;
    const int t     = threadIdx.x;
    const int fx    = t & 15;             // float4-col within stripe (0..15)
    const int ry    = t >> 4;             // row-quad-within-64 (0..15)
    const int col   = c0 + fx * 4;
    const int xsw   = fx & 3;             // LDS swizzle key ((c>>2)&3 == fx&3 for c=4fx+i)

    for (int s = 0; s < 8; ++s) {
        const int rq = s * 16 + ry;       // row-quad within chunk (0..127)
        uint32 kd[4];
#pragma unroll
        for (int i = 0; i < 4; ++i) {
            const int r = chunk * 512 + s * 64 + ry * 4 + i;   // global row
            uint32 pack = 0u;
            if (r < ROWS_R && col < COLS_R) {
                float4 m = *reinterpret_cast<const float4*>(M + (size_t)r * COLS_R + col);
                float k0 = __expf(NALPHA * m.x), k1 = __expf(NALPHA * m.y);
                float k2 = __expf(NALPHA * m.z), k3 = __expf(NALPHA * m.w);
                int lo = __builtin_amdgcn_cvt_pk_fp8_f32(k0, k1, 0, false);
                int hi = __builtin_amdgcn_cvt_pk_fp8_f32(k2, k3, lo, true);
                pack = (uint32)hi;
            }
            kd[i] = pack;
            // Krm: row-major; 16 lanes x 4B consecutive = full 64B line per row segment
            Krm[(size_t)r * DWC_P + (c0 >> 2) + fx] = pack;
        }
        // 4x4 byte transpose in registers (verified in round 3)
        uint32 x0 = __builtin_amdgcn_perm(kd[1], kd[0], 0x05010400u);
        uint32 x1 = __builtin_amdgcn_perm(kd[1], kd[0], 0x07030602u);
        uint32 x2 = __builtin_amdgcn_perm(kd[3], kd[2], 0x05010400u);
        uint32 x3 = __builtin_amdgcn_perm(kd[3], kd[2], 0x07030602u);
        uint32 o0 = __builtin_amdgcn_perm(x2, x0, 0x05040100u);   // col 4fx+0, rows rq*4..+3
        uint32 o1 = __builtin_amdgcn_perm(x2, x0, 0x07060302u);
        uint32 o2 = __builtin_amdgcn_perm(x3, x1, 0x05040100u);
        uint32 o3 = __builtin_amdgcn_perm(x3, x1, 0x07060302u);
        const int rqs = rq ^ (xsw << 2);  // swizzle rq bits 2-3 to spread banks
        T[(4 * fx + 0) * TSTRIDE + rqs] = o0;
        T[(4 * fx + 1) * TSTRIDE + rqs] = o1;
        T[(4 * fx + 2) * TSTRIDE + rqs] = o2;
        T[(4 * fx + 3) * TSTRIDE + rqs] = o3;
    }
    __syncthreads();

    // Kcm store: 2048 uint4s; 32 lanes cover 512B contiguous per column
#pragma unroll
    for (int k = 0; k < 8; ++k) {
        const int idx   = k * 256 + t;
        const int col_l = idx >> 5;        // 0..63
        const int m4    = idx & 31;        // uint4 index within column-chunk (128 dwords)
        const int mm    = m4 ^ ((col_l >> 2) & 3);   // unswizzle
        uint4 d = *reinterpret_cast<const uint4*>(&T[col_l * TSTRIDE + 4 * mm]);
        *reinterpret_cast<uint4*>(Kcm + (size_t)(c0 + col_l) * DWR_P + chunk * 128 + 4 * m4) = d;
    }
}

// ======================= persistent Sinkhorn loop + loss =======================
__global__ __launch_bounds__(NTHR, 4) void sinkhorn_persistent(
    const float*  __restrict__ M,
    const uint32* __restrict__ Krm,
    const uint32* __restrict__ Kcm,
    float* __restrict__ u_g,
    float* __restrict__ v_g,
    uint32* __restrict__ ctrl,
    float* __restrict__ err2,
    float* __restrict__ loss,
    float* __restrict__ out) {
    __shared__ float s_v[COLS_P];          // 80 KB
    __shared__ float s_red[NWAVE * 4];
    __shared__ int   s_flag;

    const int tid  = threadIdx.x;
    const int lane = tid & 63;
    const int wav  = tid >> 6;
    const int b    = blockIdx.x;
    uint32 bar = 0;

    const float4* u_g4 = reinterpret_cast<const float4*>(u_g);

    for (int t = 1; t <= 100; ++t) {
        // Checks folded into col pass: iteration t computes K^T u_{t-1}, which is
        // exactly what the reference's err check at cpt=t-1 needs (t-1 in {1,51}).
        const bool chk = (t == 2) || (t == 52);
        const int  slot = (t == 52) ? 1 : 0;

        // ---- load u into registers: lane owns u[4*(s*64+lane) .. +3] ----
        float4 u_r[8];
#pragma unroll
        for (int s = 0; s < 8; ++s) u_r[s] = u_g4[s * 64 + lane];

        // ---- column pass: x = K^T u; v_j = b/(x+eps); err from s_v (= v_{t-1}) ----
        float e = 0.f;
#pragma unroll
        for (int q = 0; q < 5; ++q) {
            const int j = b * 80 + wav * 5 + q;
            const uint32* colp = Kcm + (size_t)j * DWR_P;
            float acc = 0.f;
#pragma unroll
            for (int s = 0; s < 8; ++s) {
                uint32 kw = colp[s * 64 + lane];
                floatx2 f01 = __builtin_amdgcn_cvt_pk_f32_fp8(kw, false);
                floatx2 f23 = __builtin_amdgcn_cvt_pk_f32_fp8(kw, true);
                acc += f01.x * u_r[s].x + f01.y * u_r[s].y + f23.x * u_r[s].z + f23.y * u_r[s].w;
            }
#pragma unroll
            for (int o = 32; o; o >>= 1) acc += __shfl_xor(acc, o, 64);
            if (lane == 0) {
                v_g[j] = B_MARG / (acc + EPSV);
                if (chk && j < COLS_R) e += fabsf(s_v[j] * acc - B_MARG);
            }
        }
        if (chk) {
            if (lane == 0) s_red[wav] = e;
            __syncthreads();
            if (tid == 0) {
                float s = 0.f;
                for (int k = 0; k < NWAVE; ++k) s += s_red[k];
                if (s != 0.f) atomicAdd(&err2[slot], s);
            }
        }
        grid_barrier(ctrl, bar++);

        if (chk) {
            if (tid == 0) s_flag = (err2[slot] <= THR) ? 1 : 0;
            __syncthreads();
            // Converged at t-1: reference final state is (u_{t-1}, v_{t-1}).
            // u_g still holds u_{t-1}; s_v still holds v_{t-1} (not restaged). Break.
            if (s_flag) break;
        }

        // ---- stage v_t -> LDS ----
        {
            float4* d = reinterpret_cast<float4*>(s_v);
            const float4* srcv = reinterpret_cast<const float4*>(v_g);
#pragma unroll
            for (int k = 0; k < 5; ++k) d[k * 1024 + tid] = srcv[k * 1024 + tid];
        }
        __syncthreads();

        // ---- row pass: wave = (row-quad rq, col-segment sg); 4 rows x 1/8 width ----
        {
            const int rq = wav >> 3;           // 0..1
            const int sg = wav & 7;            // 0..7
            const int rbase = b * 8 + rq * 4;
            const uint32* kp  = Krm + (size_t)rbase * DWC_P + sg * 640;
            const float4* sv4 = reinterpret_cast<const float4*>(s_v) + sg * 640;
            float acc0 = 0.f, acc1 = 0.f, acc2 = 0.f, acc3 = 0.f;
#pragma unroll 2
            for (int s = 0; s < 10; ++s) {
                const int idx = s * 64 + lane;
                float4 vv = sv4[idx];
                uint32 k0 = kp[idx];
                uint32 k1 = kp[idx + DWC_P];
                uint32 k2 = kp[idx + 2 * DWC_P];
                uint32 k3 = kp[idx + 3 * DWC_P];
                floatx2 a0 = __builtin_amdgcn_cvt_pk_f32_fp8(k0, false);
                floatx2 b0 = __builtin_amdgcn_cvt_pk_f32_fp8(k0, true);
                acc0 += a0.x * vv.x + a0.y * vv.y + b0.x * vv.z + b0.y * vv.w;
                floatx2 a1 = __builtin_amdgcn_cvt_pk_f32_fp8(k1, false);
                floatx2 b1 = __builtin_amdgcn_cvt_pk_f32_fp8(k1, true);
                acc1 += a1.x * vv.x + a1.y * vv.y + b1.x * vv.z + b1.y * vv.w;
                floatx2 a2 = __builtin_amdgcn_cvt_pk_f32_fp8(k2, false);
                floatx2 b2 = __builtin_amdgcn_cvt_pk_f32_fp8(k2, true);
                acc2 += a2.x * vv.x + a2.y * vv.y + b2.x * vv.z + b2.y * vv.w;
                floatx2 a3 = __builtin_amdgcn_cvt_pk_f32_fp8(k3, false);
                floatx2 b3 = __builtin_amdgcn_cvt_pk_f32_fp8(k3, true);
                acc3 += a3.x * vv.x + a3.y * vv.y + b3.x * vv.z + b3.y * vv.w;
            }
#pragma unroll
            for (int o = 32; o; o >>= 1) {
                acc0 += __shfl_xor(acc0, o, 64);
                acc1 += __shfl_xor(acc1, o, 64);
                acc2 += __shfl_xor(acc2, o, 64);
                acc3 += __shfl_xor(acc3, o, 64);
            }
            if (lane == 0) {
                s_red[wav * 4 + 0] = acc0;
                s_red[wav * 4 + 1] = acc1;
                s_red[wav * 4 + 2] = acc2;
                s_red[wav * 4 + 3] = acc3;
            }
        }
        __syncthreads();
        if (tid < 8) {
            const int row = b * 8 + tid;
            if (row < ROWS_R) {
                const int rq2 = tid >> 2, i = tid & 3;
                float s = 0.f;
#pragma unroll
                for (int sg = 0; sg < 8; ++sg) s += s_red[(rq2 * 8 + sg) * 4 + i];
                u_g[row] = A_MARG / (s + EPSV);
            }
        }
        grid_barrier(ctrl, bar++);
    }

    // ---- loss = sum_ij u_i exp(-20 M_ij) v_j M_ij (fp32 from M; s_v = final v) ----
    {
        const float4* sv4 = reinterpret_cast<const float4*>(s_v);
        const int rw = b * NWAVE + wav;       // 4096 waves >= 2000 rows
        if (rw < ROWS_R) {
            const float4* mrow = reinterpret_cast<const float4*>(M + (size_t)rw * COLS_R);
            float acc = 0.f;
            for (int ci = lane; ci < 5000; ci += 64) {
                float4 m = mrow[ci];
                float4 vv = sv4[ci];
                acc += __expf(NALPHA * m.x) * vv.x * m.x;
                acc += __expf(NALPHA * m.y) * vv.y * m.y;
                acc += __expf(NALPHA * m.z) * vv.z * m.z;
                acc += __expf(NALPHA * m.w) * vv.w * m.w;
            }
#pragma unroll
            for (int o = 32; o; o >>= 1) acc += __shfl_xor(acc, o, 64);
            if (lane == 0) atomicAdd(loss, acc * u_g[rw]);
        }
    }
    grid_barrier(ctrl, bar++);
    if (b == 0 && tid == 0) out[0] = *loss * 100.0f;
}

// ======================= fallback path (tiny workspace) =======================

__device__ __forceinline__ float block_reduce_sum256(float v) {
#pragma unroll
    for (int o = 32; o; o >>= 1) v += __shfl_down(v, o, 64);
    __shared__ float smem[4];
    int lane = threadIdx.x & 63, w = threadIdx.x >> 6;
    if (lane == 0) smem[w] = v;
    __syncthreads();
    v = (threadIdx.x < 4) ? smem[threadIdx.x] : 0.0f;
    v += __shfl_down(v, 2, 64);
    v += __shfl_down(v, 1, 64);
    return v;
}

__global__ __launch_bounds__(256) void fb_init(float* u, float* vden, int* done, float* err, float* loss) {
    int idx = blockIdx.x * 256 + threadIdx.x;
    if (idx == 0) { *done = 0; *err = 0.0f; *loss = 0.0f; }
    if (idx < ROWS_R) u[idx] = A_MARG;
    if (idx < COLS_R) vden[idx] = 0.0f;
}
__global__ __launch_bounds__(256) void fb_colpass(const float* __restrict__ M, const float* __restrict__ u,
                                                  float* __restrict__ vden, const int* __restrict__ done) {
    if (*done) return;
    int c4 = blockIdx.x * 256 + threadIdx.x;
    if (c4 >= 5000) return;
    int r0 = blockIdx.y * 50;
    float4 acc = make_float4(0.f, 0.f, 0.f, 0.f);
    for (int r = r0; r < r0 + 50; ++r) {
        float ui = u[r];
        float4 mm = reinterpret_cast<const float4*>(M)[(size_t)r * 5000 + c4];
        acc.x += __expf(NALPHA * mm.x) * ui; acc.y += __expf(NALPHA * mm.y) * ui;
        acc.z += __expf(NALPHA * mm.z) * ui; acc.w += __expf(NALPHA * mm.w) * ui;
    }
    atomicAdd(&vden[c4 * 4 + 0], acc.x); atomicAdd(&vden[c4 * 4 + 1], acc.y);
    atomicAdd(&vden[c4 * 4 + 2], acc.z); atomicAdd(&vden[c4 * 4 + 3], acc.w);
}
__global__ __launch_bounds__(256) void fb_finv(float* v, float* vden, const int* done) {
    if (*done) return;
    int j = blockIdx.x * 256 + threadIdx.x;
    if (j < COLS_R) { v[j] = B_MARG / (vden[j] + EPSV); vden[j] = 0.0f; }
}
__global__ __launch_bounds__(256) void fb_rowpass(const float* __restrict__ M, const float* __restrict__ v,
                                                  float* __restrict__ u, const int* __restrict__ done) {
    if (*done) return;
    int row = blockIdx.x;
    const float4* v4 = reinterpret_cast<const float4*>(v);
    float acc = 0.0f;
    for (int c4 = threadIdx.x; c4 < 5000; c4 += 256) {
        float4 mm = reinterpret_cast<const float4*>(M)[(size_t)row * 5000 + c4];
        float4 vv = v4[c4];
        acc += __expf(NALPHA * mm.x) * vv.x + __expf(NALPHA * mm.y) * vv.y
             + __expf(NALPHA * mm.z) * vv.z + __expf(NALPHA * mm.w) * vv.w;
    }
    float s = block_reduce_sum256(acc);
    if (threadIdx.x == 0) u[row] = A_MARG / (s + EPSV);
}
__global__ __launch_bounds__(256) void fb_errfin(const float* v, float* vden, float* err, const int* done) {
    if (*done) return;
    int j = blockIdx.x * 256 + threadIdx.x;
    float local = 0.0f;
    if (j < COLS_R) { local = fabsf(v[j] * vden[j] - B_MARG); vden[j] = 0.0f; }
    float s = block_reduce_sum256(local);
    if (threadIdx.x == 0) atomicAdd(err, s);
}
__global__ void fb_check(int* done, float* err) {
    if (threadIdx.x == 0) { if (!*done && *err <= THR) *done = 1; *err = 0.0f; }
}
__global__ __launch_bounds__(256) void fb_loss(const float* __restrict__ M, const float* __restrict__ u,
                                               const float* __restrict__ v, float* __restrict__ loss) {
    int row = blockIdx.x;
    const float4* M4p = reinterpret_cast<const float4*>(M + (size_t)row * COLS_R);
    const float4* v4 = reinterpret_cast<const float4*>(v);
    float acc = 0.0f;
    for (int c4 = threadIdx.x; c4 < 5000; c4 += 256) {
        float4 mm = M4p[c4]; float4 vv = v4[c4];
        acc += __expf(NALPHA * mm.x) * vv.x * mm.x + __expf(NALPHA * mm.y) * vv.y * mm.y
             + __expf(NALPHA * mm.z) * vv.z * mm.z + __expf(NALPHA * mm.w) * vv.w * mm.w;
    }
    float s = block_reduce_sum256(acc);
    if (threadIdx.x == 0) atomicAdd(loss, s * u[row]);
}
__global__ void fb_writeout(float* out, const float* loss) {
    if (threadIdx.x == 0) out[0] = *loss * 100.0f;
}

// ======================= host launch =======================

extern "C" void kernel_launch(void* const* d_in, const int* in_sizes, int n_in,
                              void* d_out, int out_size, void* d_ws, size_t ws_size,
                              hipStream_t stream) {
    const float* M = (const float*)d_in[0];
    char* base = (char*)d_ws;

    const size_t OFF_CTRL = 0;                        // uint32[2048] (8 KB; 1280 used)
    const size_t OFF_ERR  = 8192;
    const size_t OFF_LOSS = 8320;
    const size_t OFF_U    = 8448;                     // 2048 f
    const size_t OFF_V    = OFF_U + 8192;             // 20480 f -> ends 98560 (256-aligned)
    const size_t OFF_KRM  = OFF_V + 81920;
    const size_t K_BYTES  = (size_t)ROWS_P * COLS_P;  // 41.94 MB
    const size_t OFF_KCM  = OFF_KRM + K_BYTES;
    const size_t NEED     = OFF_KCM + K_BYTES;        // ~84 MB

    if (ws_size >= NEED) {
        uint32* ctrl = (uint32*)(base + OFF_CTRL);
        float*  err2 = (float*)(base + OFF_ERR);
        float*  loss = (float*)(base + OFF_LOSS);
        float*  u_g  = (float*)(base + OFF_U);
        float*  v_g  = (float*)(base + OFF_V);
        uint32* Krm  = (uint32*)(base + OFF_KRM);
        uint32* Kcm  = (uint32*)(base + OFF_KCM);

        build_v2<<<1280, 256, 0, stream>>>(M, Krm, Kcm, u_g, ctrl, err2, loss);
        sinkhorn_persistent<<<NBLK, NTHR, 0, stream>>>(M, Krm, Kcm, u_g, v_g,
                                                       ctrl, err2, loss, (float*)d_out);
    } else {
        int*   done = (int*)(base + 0);
        float* err  = (float*)(base + 8);
        float* loss = (float*)(base + 16);
        float* u    = (float*)(base + 64);
        float* v    = (float*)(base + 64 + 8192);
        float* vden = (float*)(base + 64 + 8192 + 80000);

        fb_init<<<79, 256, 0, stream>>>(u, vden, done, err, loss);
        dim3 cgrid(20, 40);
        for (int t = 1; t <= 100; ++t) {
            fb_colpass<<<cgrid, 256, 0, stream>>>(M, u, vden, done);
            fb_finv<<<79, 256, 0, stream>>>(v, vden, done);
            fb_rowpass<<<ROWS_R, 256, 0, stream>>>(M, v, u, done);
            if (t == 1 || t == 51) {
                fb_colpass<<<cgrid, 256, 0, stream>>>(M, u, vden, done);
                fb_errfin<<<79, 256, 0, stream>>>(v, vden, err, done);
                fb_check<<<1, 64, 0, stream>>>(done, err);
            }
        }
        fb_loss<<<ROWS_R, 256, 0, stream>>>(M, u, v, loss);
        fb_writeout<<<1, 64, 0, stream>>>((float*)d_out, loss);
    }
}

// Round 5
// 393.275 us; speedup vs baseline: 2.0564x; 1.1619x over previous
//
#include <hip/hip_runtime.h>
#include <hip/hip_fp16.h>

typedef unsigned int uint32;
typedef float floatx2 __attribute__((ext_vector_type(2)));

#define ROWS_R 2000
#define COLS_R 20000
#define ROWS_P 2048
#define COLS_P 20480
#define DWC_P  (COLS_P/4)   /* 5120 fp8-dwords per padded row */
#define DWR_P  (ROWS_P/4)   /* 512 fp8-dwords per padded col  */
#define NBLK   256
#define NTHR   1024
#define NWAVE  16
#define TSTRIDE 132         /* LDS transpose tile stride (dwords) */

static constexpr float A_MARG = 1.0f / 2000.0f;
static constexpr float B_MARG = 1.0f / 20000.0f;
static constexpr float EPSV   = 1e-16f;
static constexpr float THR    = 0.005f;
static constexpr float NALPHA = -20.0f;

// ======================= two-level grid barrier =======================
// ctrl dwords: [0]=root_cnt, [64]=root_gen, [128+g*64]=group_cnt, [768+g*64]=group_gen.
__device__ __forceinline__ void grid_barrier(uint32* ctrl, uint32 rnd) {
    __syncthreads();
    if (threadIdx.x == 0) {
        const int gid = (int)(blockIdx.x >> 5);
        uint32* gcnt = ctrl + 128 + gid * 64;
        uint32* ggen = ctrl + 768 + gid * 64;
        __threadfence();
        uint32 a = __hip_atomic_fetch_add(gcnt, 1u, __ATOMIC_RELAXED, __HIP_MEMORY_SCOPE_AGENT);
        if (a == rnd * 32u + 31u) {
            uint32 r = __hip_atomic_fetch_add(ctrl, 1u, __ATOMIC_RELAXED, __HIP_MEMORY_SCOPE_AGENT);
            if (r == rnd * 8u + 7u) {
                __hip_atomic_fetch_add(ctrl + 64, 1u, __ATOMIC_RELAXED, __HIP_MEMORY_SCOPE_AGENT);
            } else {
                while (__hip_atomic_load(ctrl + 64, __ATOMIC_RELAXED, __HIP_MEMORY_SCOPE_AGENT) < rnd + 1u)
                    __builtin_amdgcn_s_sleep(1);
            }
            __hip_atomic_fetch_add(ggen, 1u, __ATOMIC_RELAXED, __HIP_MEMORY_SCOPE_AGENT);
        } else {
            while (__hip_atomic_load(ggen, __ATOMIC_RELAXED, __HIP_MEMORY_SCOPE_AGENT) < rnd + 1u)
                __builtin_amdgcn_s_sleep(1);
        }
        __threadfence();
    }
    __syncthreads();
}

// ======================= init: ctrl/err/loss/u (ws is poisoned each launch) =======================
__global__ __launch_bounds__(256) void init_kernel(float* __restrict__ u_g,
                                                   uint32* __restrict__ ctrl,
                                                   float* __restrict__ err2,
                                                   float* __restrict__ loss) {
    int idx = blockIdx.x * 256 + threadIdx.x;
    if (idx < 1280) ctrl[idx] = 0u;
    if (idx == 0) { err2[0] = 0.f; err2[1] = 0.f; *loss = 0.f; }
    if (idx < 2048) u_g[idx] = (idx < ROWS_R) ? A_MARG : 0.0f;
}

// ======================= fused: build K (fp8, row+col major) then Sinkhorn + loss =======================
__global__ __launch_bounds__(NTHR, 1) void sinkhorn_fused(
    const float*  __restrict__ M,
    uint32* __restrict__ Krm,
    uint32* __restrict__ Kcm,
    float* __restrict__ u_g,
    float* __restrict__ v_g,
    uint32* __restrict__ ctrl,
    float* __restrict__ err2,
    float* __restrict__ loss,
    float* __restrict__ out) {
    __shared__ float  s_v[COLS_P];          // 80 KB
    __shared__ uint32 T[64 * TSTRIDE];      // 33.8 KB build transpose tile
    __shared__ float  s_red[NWAVE * 4];
    __shared__ int    s_flag;

    const int tid  = threadIdx.x;
    const int lane = tid & 63;
    const int wav  = tid >> 6;
    const int b    = blockIdx.x;
    uint32 bar = 0;

    // ================= build phase: 1280 tiles (64 cols x 512 rows), 5 per block =================
    {
        const int fx  = tid & 15;           // float4-col in stripe
        const int ry  = tid >> 4;           // 0..63 row-quad-subindex
        const int xsw = fx & 3;
        for (int tt = 0; tt < 5; ++tt) {
            const int tile  = b * 5 + tt;
            const int c64   = tile % 320;
            const int chunk = tile / 320;
            const int c0    = c64 * 64;
            const int col   = c0 + fx * 4;
#pragma unroll
            for (int s = 0; s < 2; ++s) {
                const int rq = s * 64 + ry;            // 0..127
                uint32 kd[4];
#pragma unroll
                for (int i = 0; i < 4; ++i) {
                    const int r = chunk * 512 + rq * 4 + i;
                    uint32 pack = 0u;
                    if (r < ROWS_R && col < COLS_R) {
                        float4 m = *reinterpret_cast<const float4*>(M + (size_t)r * COLS_R + col);
                        float k0 = __expf(NALPHA * m.x), k1 = __expf(NALPHA * m.y);
                        float k2 = __expf(NALPHA * m.z), k3 = __expf(NALPHA * m.w);
                        int lo = __builtin_amdgcn_cvt_pk_fp8_f32(k0, k1, 0, false);
                        int hi = __builtin_amdgcn_cvt_pk_fp8_f32(k2, k3, lo, true);
                        pack = (uint32)hi;
                    }
                    kd[i] = pack;
                    Krm[(size_t)(chunk * 512 + rq * 4 + i) * DWC_P + (c0 >> 2) + fx] = pack;
                }
                uint32 x0 = __builtin_amdgcn_perm(kd[1], kd[0], 0x05010400u);
                uint32 x1 = __builtin_amdgcn_perm(kd[1], kd[0], 0x07030602u);
                uint32 x2 = __builtin_amdgcn_perm(kd[3], kd[2], 0x05010400u);
                uint32 x3 = __builtin_amdgcn_perm(kd[3], kd[2], 0x07030602u);
                uint32 o0 = __builtin_amdgcn_perm(x2, x0, 0x05040100u);
                uint32 o1 = __builtin_amdgcn_perm(x2, x0, 0x07060302u);
                uint32 o2 = __builtin_amdgcn_perm(x3, x1, 0x05040100u);
                uint32 o3 = __builtin_amdgcn_perm(x3, x1, 0x07060302u);
                const int rqs = rq ^ (xsw << 2);
                T[(4 * fx + 0) * TSTRIDE + rqs] = o0;
                T[(4 * fx + 1) * TSTRIDE + rqs] = o1;
                T[(4 * fx + 2) * TSTRIDE + rqs] = o2;
                T[(4 * fx + 3) * TSTRIDE + rqs] = o3;
            }
            __syncthreads();
#pragma unroll
            for (int k = 0; k < 2; ++k) {
                const int idx   = k * 1024 + tid;
                const int col_l = idx >> 5;
                const int m4    = idx & 31;
                const int mm    = m4 ^ ((col_l >> 2) & 3);
                uint4 d = *reinterpret_cast<const uint4*>(&T[col_l * TSTRIDE + 4 * mm]);
                *reinterpret_cast<uint4*>(Kcm + (size_t)(c0 + col_l) * DWR_P + chunk * 128 + 4 * m4) = d;
            }
            __syncthreads();
        }
    }
    grid_barrier(ctrl, bar++);

    // ================= Sinkhorn loop =================
    const float4* u_g4 = reinterpret_cast<const float4*>(u_g);

    for (int t = 1; t <= 100; ++t) {
        // check folded into col pass: iteration t computes K^T u_{t-1} == err input at cpt=t-1
        const bool chk = (t == 2) || (t == 52);
        const int  slot = (t == 52) ? 1 : 0;

        float4 u_r[8];
#pragma unroll
        for (int s = 0; s < 8; ++s) u_r[s] = u_g4[s * 64 + lane];

        float e = 0.f;
#pragma unroll
        for (int q = 0; q < 5; ++q) {
            const int j = b * 80 + wav * 5 + q;
            const uint32* colp = Kcm + (size_t)j * DWR_P;
            float acc = 0.f;
#pragma unroll
            for (int s = 0; s < 8; ++s) {
                uint32 kw = colp[s * 64 + lane];
                floatx2 f01 = __builtin_amdgcn_cvt_pk_f32_fp8(kw, false);
                floatx2 f23 = __builtin_amdgcn_cvt_pk_f32_fp8(kw, true);
                acc += f01.x * u_r[s].x + f01.y * u_r[s].y + f23.x * u_r[s].z + f23.y * u_r[s].w;
            }
#pragma unroll
            for (int o = 32; o; o >>= 1) acc += __shfl_xor(acc, o, 64);
            if (lane == 0) {
                v_g[j] = B_MARG / (acc + EPSV);
                if (chk && j < COLS_R) e += fabsf(s_v[j] * acc - B_MARG);
            }
        }
        if (chk) {
            if (lane == 0) s_red[wav] = e;
            __syncthreads();
            if (tid == 0) {
                float s = 0.f;
                for (int k = 0; k < NWAVE; ++k) s += s_red[k];
                if (s != 0.f) atomicAdd(&err2[slot], s);
            }
        }
        grid_barrier(ctrl, bar++);

        if (chk) {
            if (tid == 0) s_flag = (err2[slot] <= THR) ? 1 : 0;
            __syncthreads();
            if (s_flag) break;   // final state = (u_{t-1} in u_g, v_{t-1} in s_v)
        }

        // stage v_t -> LDS
        {
            float4* d = reinterpret_cast<float4*>(s_v);
            const float4* srcv = reinterpret_cast<const float4*>(v_g);
#pragma unroll
            for (int k = 0; k < 5; ++k) d[k * 1024 + tid] = srcv[k * 1024 + tid];
        }
        __syncthreads();

        // row pass: wave = (row-quad rq, col-segment sg); 4 rows x 1/8 width
        {
            const int rq = wav >> 3;
            const int sg = wav & 7;
            const int rbase = b * 8 + rq * 4;
            const uint32* kp  = Krm + (size_t)rbase * DWC_P + sg * 640;
            const float4* sv4 = reinterpret_cast<const float4*>(s_v) + sg * 640;
            float acc0 = 0.f, acc1 = 0.f, acc2 = 0.f, acc3 = 0.f;
#pragma unroll 2
            for (int s = 0; s < 10; ++s) {
                const int idx = s * 64 + lane;
                float4 vv = sv4[idx];
                uint32 k0 = kp[idx];
                uint32 k1 = kp[idx + DWC_P];
                uint32 k2 = kp[idx + 2 * DWC_P];
                uint32 k3 = kp[idx + 3 * DWC_P];
                floatx2 a0 = __builtin_amdgcn_cvt_pk_f32_fp8(k0, false);
                floatx2 b0 = __builtin_amdgcn_cvt_pk_f32_fp8(k0, true);
                acc0 += a0.x * vv.x + a0.y * vv.y + b0.x * vv.z + b0.y * vv.w;
                floatx2 a1 = __builtin_amdgcn_cvt_pk_f32_fp8(k1, false);
                floatx2 b1 = __builtin_amdgcn_cvt_pk_f32_fp8(k1, true);
                acc1 += a1.x * vv.x + a1.y * vv.y + b1.x * vv.z + b1.y * vv.w;
                floatx2 a2 = __builtin_amdgcn_cvt_pk_f32_fp8(k2, false);
                floatx2 b2 = __builtin_amdgcn_cvt_pk_f32_fp8(k2, true);
                acc2 += a2.x * vv.x + a2.y * vv.y + b2.x * vv.z + b2.y * vv.w;
                floatx2 a3 = __builtin_amdgcn_cvt_pk_f32_fp8(k3, false);
                floatx2 b3 = __builtin_amdgcn_cvt_pk_f32_fp8(k3, true);
                acc3 += a3.x * vv.x + a3.y * vv.y + b3.x * vv.z + b3.y * vv.w;
            }
#pragma unroll
            for (int o = 32; o; o >>= 1) {
                acc0 += __shfl_xor(acc0, o, 64);
                acc1 += __shfl_xor(acc1, o, 64);
                acc2 += __shfl_xor(acc2, o, 64);
                acc3 += __shfl_xor(acc3, o, 64);
            }
            if (lane == 0) {
                s_red[wav * 4 + 0] = acc0;
                s_red[wav * 4 + 1] = acc1;
                s_red[wav * 4 + 2] = acc2;
                s_red[wav * 4 + 3] = acc3;
            }
        }
        __syncthreads();
        if (tid < 8) {
            const int row = b * 8 + tid;
            if (row < ROWS_R) {
                const int rq2 = tid >> 2, i = tid & 3;
                float s = 0.f;
#pragma unroll
                for (int sg = 0; sg < 8; ++sg) s += s_red[(rq2 * 8 + sg) * 4 + i];
                u_g[row] = A_MARG / (s + EPSV);
            }
        }
        grid_barrier(ctrl, bar++);
    }

    // ================= loss = sum_ij u_i exp(-20 M_ij) v_j M_ij =================
    {
        const float4* sv4 = reinterpret_cast<const float4*>(s_v);
        const int rw = b * NWAVE + wav;
        if (rw < ROWS_R) {
            const float4* mrow = reinterpret_cast<const float4*>(M + (size_t)rw * COLS_R);
            float acc = 0.f;
            for (int ci = lane; ci < 5000; ci += 64) {
                float4 m = mrow[ci];
                float4 vv = sv4[ci];
                acc += __expf(NALPHA * m.x) * vv.x * m.x;
                acc += __expf(NALPHA * m.y) * vv.y * m.y;
                acc += __expf(NALPHA * m.z) * vv.z * m.z;
                acc += __expf(NALPHA * m.w) * vv.w * m.w;
            }
#pragma unroll
            for (int o = 32; o; o >>= 1) acc += __shfl_xor(acc, o, 64);
            if (lane == 0) atomicAdd(loss, acc * u_g[rw]);
        }
    }
    grid_barrier(ctrl, bar++);
    if (b == 0 && tid == 0) out[0] = *loss * 100.0f;
}

// ======================= fallback path (tiny workspace) =======================

__device__ __forceinline__ float block_reduce_sum256(float v) {
#pragma unroll
    for (int o = 32; o; o >>= 1) v += __shfl_down(v, o, 64);
    __shared__ float smem[4];
    int lane = threadIdx.x & 63, w = threadIdx.x >> 6;
    if (lane == 0) smem[w] = v;
    __syncthreads();
    v = (threadIdx.x < 4) ? smem[threadIdx.x] : 0.0f;
    v += __shfl_down(v, 2, 64);
    v += __shfl_down(v, 1, 64);
    return v;
}

__global__ __launch_bounds__(256) void fb_init(float* u, float* vden, int* done, float* err, float* loss) {
    int idx = blockIdx.x * 256 + threadIdx.x;
    if (idx == 0) { *done = 0; *err = 0.0f; *loss = 0.0f; }
    if (idx < ROWS_R) u[idx] = A_MARG;
    if (idx < COLS_R) vden[idx] = 0.0f;
}
__global__ __launch_bounds__(256) void fb_colpass(const float* __restrict__ M, const float* __restrict__ u,
                                                  float* __restrict__ vden, const int* __restrict__ done) {
    if (*done) return;
    int c4 = blockIdx.x * 256 + threadIdx.x;
    if (c4 >= 5000) return;
    int r0 = blockIdx.y * 50;
    float4 acc = make_float4(0.f, 0.f, 0.f, 0.f);
    for (int r = r0; r < r0 + 50; ++r) {
        float ui = u[r];
        float4 mm = reinterpret_cast<const float4*>(M)[(size_t)r * 5000 + c4];
        acc.x += __expf(NALPHA * mm.x) * ui; acc.y += __expf(NALPHA * mm.y) * ui;
        acc.z += __expf(NALPHA * mm.z) * ui; acc.w += __expf(NALPHA * mm.w) * ui;
    }
    atomicAdd(&vden[c4 * 4 + 0], acc.x); atomicAdd(&vden[c4 * 4 + 1], acc.y);
    atomicAdd(&vden[c4 * 4 + 2], acc.z); atomicAdd(&vden[c4 * 4 + 3], acc.w);
}
__global__ __launch_bounds__(256) void fb_finv(float* v, float* vden, const int* done) {
    if (*done) return;
    int j = blockIdx.x * 256 + threadIdx.x;
    if (j < COLS_R) { v[j] = B_MARG / (vden[j] + EPSV); vden[j] = 0.0f; }
}
__global__ __launch_bounds__(256) void fb_rowpass(const float* __restrict__ M, const float* __restrict__ v,
                                                  float* __restrict__ u, const int* __restrict__ done) {
    if (*done) return;
    int row = blockIdx.x;
    const float4* v4 = reinterpret_cast<const float4*>(v);
    float acc = 0.0f;
    for (int c4 = threadIdx.x; c4 < 5000; c4 += 256) {
        float4 mm = reinterpret_cast<const float4*>(M)[(size_t)row * 5000 + c4];
        float4 vv = v4[c4];
        acc += __expf(NALPHA * mm.x) * vv.x + __expf(NALPHA * mm.y) * vv.y
             + __expf(NALPHA * mm.z) * vv.z + __expf(NALPHA * mm.w) * vv.w;
    }
    float s = block_reduce_sum256(acc);
    if (threadIdx.x == 0) u[row] = A_MARG / (s + EPSV);
}
__global__ __launch_bounds__(256) void fb_errfin(const float* v, float* vden, float* err, const int* done) {
    if (*done) return;
    int j = blockIdx.x * 256 + threadIdx.x;
    float local = 0.0f;
    if (j < COLS_R) { local = fabsf(v[j] * vden[j] - B_MARG); vden[j] = 0.0f; }
    float s = block_reduce_sum256(local);
    if (threadIdx.x == 0) atomicAdd(err, s);
}
__global__ void fb_check(int* done, float* err) {
    if (threadIdx.x == 0) { if (!*done && *err <= THR) *done = 1; *err = 0.0f; }
}
__global__ __launch_bounds__(256) void fb_loss(const float* __restrict__ M, const float* __restrict__ u,
                                               const float* __restrict__ v, float* __restrict__ loss) {
    int row = blockIdx.x;
    const float4* M4p = reinterpret_cast<const float4*>(M + (size_t)row * COLS_R);
    const float4* v4 = reinterpret_cast<const float4*>(v);
    float acc = 0.0f;
    for (int c4 = threadIdx.x; c4 < 5000; c4 += 256) {
        float4 mm = M4p[c4]; float4 vv = v4[c4];
        acc += __expf(NALPHA * mm.x) * vv.x * mm.x + __expf(NALPHA * mm.y) * vv.y * mm.y
             + __expf(NALPHA * mm.z) * vv.z * mm.z + __expf(NALPHA * mm.w) * vv.w * mm.w;
    }
    float s = block_reduce_sum256(acc);
    if (threadIdx.x == 0) atomicAdd(loss, s * u[row]);
}
__global__ void fb_writeout(float* out, const float* loss) {
    if (threadIdx.x == 0) out[0] = *loss * 100.0f;
}

// ======================= host launch =======================

extern "C" void kernel_launch(void* const* d_in, const int* in_sizes, int n_in,
                              void* d_out, int out_size, void* d_ws, size_t ws_size,
                              hipStream_t stream) {
    const float* M = (const float*)d_in[0];
    char* base = (char*)d_ws;

    const size_t OFF_CTRL = 0;                        // uint32[2048] (8 KB; 1280 used)
    const size_t OFF_ERR  = 8192;
    const size_t OFF_LOSS = 8320;
    const size_t OFF_U    = 8448;                     // 2048 f
    const size_t OFF_V    = OFF_U + 8192;             // 20480 f
    const size_t OFF_KRM  = OFF_V + 81920;
    const size_t K_BYTES  = (size_t)ROWS_P * COLS_P;  // 41.94 MB
    const size_t OFF_KCM  = OFF_KRM + K_BYTES;
    const size_t NEED     = OFF_KCM + K_BYTES;        // ~84 MB

    if (ws_size >= NEED) {
        uint32* ctrl = (uint32*)(base + OFF_CTRL);
        float*  err2 = (float*)(base + OFF_ERR);
        float*  loss = (float*)(base + OFF_LOSS);
        float*  u_g  = (float*)(base + OFF_U);
        float*  v_g  = (float*)(base + OFF_V);
        uint32* Krm  = (uint32*)(base + OFF_KRM);
        uint32* Kcm  = (uint32*)(base + OFF_KCM);

        init_kernel<<<8, 256, 0, stream>>>(u_g, ctrl, err2, loss);
        sinkhorn_fused<<<NBLK, NTHR, 0, stream>>>(M, Krm, Kcm, u_g, v_g,
                                                  ctrl, err2, loss, (float*)d_out);
    } else {
        int*   done = (int*)(base + 0);
        float* err  = (float*)(base + 8);
        float* loss = (float*)(base + 16);
        float* u    = (float*)(base + 64);
        float* v    = (float*)(base + 64 + 8192);
        float* vden = (float*)(base + 64 + 8192 + 80000);

        fb_init<<<79, 256, 0, stream>>>(u, vden, done, err, loss);
        dim3 cgrid(20, 40);
        for (int t = 1; t <= 100; ++t) {
            fb_colpass<<<cgrid, 256, 0, stream>>>(M, u, vden, done);
            fb_finv<<<79, 256, 0, stream>>>(v, vden, done);
            fb_rowpass<<<ROWS_R, 256, 0, stream>>>(M, v, u, done);
            if (t == 1 || t == 51) {
                fb_colpass<<<cgrid, 256, 0, stream>>>(M, u, vden, done);
                fb_errfin<<<79, 256, 0, stream>>>(v, vden, err, done);
                fb_check<<<1, 64, 0, stream>>>(done, err);
            }
        }
        fb_loss<<<ROWS_R, 256, 0, stream>>>(M, u, v, loss);
        fb_writeout<<<1, 64, 0, stream>>>((float*)d_out, loss);
    }
}

// Round 6
// 365.695 us; speedup vs baseline: 2.2115x; 1.0754x over previous
//
#include <hip/hip_runtime.h>

typedef unsigned int uint32;
typedef float floatx2 __attribute__((ext_vector_type(2)));

#define ROWS_R 2000
#define COLS_R 20000
#define NBLK   256
#define NTHR   1024
#define NWAVE  16
#define CPB    80          /* columns per block: 250 blocks cover 20000; 250..255 all-pad */
#define CSTR   501         /* LDS column stride in dwords (2004 B): 500 data + 1 zero pad */
#define KDW    (CPB*CSTR)  /* 40080 dwords = 160320 B */
#define KGUARD 16          /* zero guard so col-pass tail reads (d<=511) stay in-bounds */

static constexpr float A_MARG = 1.0f / 2000.0f;
static constexpr float B_MARG = 1.0f / 20000.0f;
static constexpr float EPSV   = 1e-16f;
static constexpr float THR    = 0.005f;
static constexpr float NALPHA = -20.0f;

// ======================= two-level grid barrier =======================
// ctrl dwords: [0]=root_cnt, [64]=root_gen, [128+g*64]=group_cnt, [768+g*64]=group_gen.
__device__ __forceinline__ void grid_barrier(uint32* ctrl, uint32 rnd) {
    __syncthreads();
    if (threadIdx.x == 0) {
        const int gid = (int)(blockIdx.x >> 5);
        uint32* gcnt = ctrl + 128 + gid * 64;
        uint32* ggen = ctrl + 768 + gid * 64;
        __threadfence();
        uint32 a = __hip_atomic_fetch_add(gcnt, 1u, __ATOMIC_RELAXED, __HIP_MEMORY_SCOPE_AGENT);
        if (a == rnd * 32u + 31u) {
            uint32 r = __hip_atomic_fetch_add(ctrl, 1u, __ATOMIC_RELAXED, __HIP_MEMORY_SCOPE_AGENT);
            if (r == rnd * 8u + 7u) {
                __hip_atomic_fetch_add(ctrl + 64, 1u, __ATOMIC_RELAXED, __HIP_MEMORY_SCOPE_AGENT);
            } else {
                while (__hip_atomic_load(ctrl + 64, __ATOMIC_RELAXED, __HIP_MEMORY_SCOPE_AGENT) < rnd + 1u)
                    __builtin_amdgcn_s_sleep(1);
            }
            __hip_atomic_fetch_add(ggen, 1u, __ATOMIC_RELAXED, __HIP_MEMORY_SCOPE_AGENT);
        } else {
            while (__hip_atomic_load(ggen, __ATOMIC_RELAXED, __HIP_MEMORY_SCOPE_AGENT) < rnd + 1u)
                __builtin_amdgcn_s_sleep(1);
        }
        __threadfence();
    }
    __syncthreads();
}

// ======================= init (ws is poisoned before every launch) =======================
__global__ __launch_bounds__(256) void init_kernel(float* __restrict__ u_g,
                                                   uint32* __restrict__ ctrl,
                                                   float* __restrict__ err2,
                                                   float* __restrict__ loss) {
    int idx = blockIdx.x * 256 + threadIdx.x;
    if (idx < 1280) ctrl[idx] = 0u;
    if (idx == 0) { err2[0] = 0.f; err2[1] = 0.f; *loss = 0.f; }
    if (idx < 2048) u_g[idx] = (idx < ROWS_R) ? A_MARG : 0.0f;   // zero pad rows!
}

// ======================= LDS-resident-K Sinkhorn =======================
// Block b owns columns [80b, 80b+80). K stripe lives in LDS (fp8, col-major,
// stride 2004 B). v is block-local. Only global exchange: P partials + u.
__global__ __launch_bounds__(NTHR, 1) void sinkhorn_lds(
    const float* __restrict__ M,
    float* __restrict__ u_g,          // 2048 floats (pad rows = 0)
    float* __restrict__ P,            // 256 x 2048 floats
    uint32* __restrict__ ctrl,
    float* __restrict__ err2,
    float* __restrict__ loss,
    float* __restrict__ out) {
    __shared__ uint32 sK[KDW + KGUARD];   // ~160.4 KB
    __shared__ float  s_vloc[CPB];
    __shared__ float  s_vprev[CPB];
    __shared__ float  s_red[NWAVE * 8];
    __shared__ int    s_flag;

    const int tid  = threadIdx.x;
    const int lane = tid & 63;
    const int wav  = tid >> 6;
    const int b    = blockIdx.x;
    const int j0   = b * CPB;
    uint32 bar = 0;

    // ---------------- build: zero LDS, then pack exp(-20 M) fp8 col-major ----------------
    for (int i = tid; i < KDW + KGUARD; i += NTHR) sK[i] = 0u;
    __syncthreads();
    for (int q = wav; q < 500; q += NWAVE) {          // row-quad q -> rows 4q..4q+3
#pragma unroll
        for (int ph = 0; ph < 2; ++ph) {
            const int cl = ph * 64 + lane;            // local col 0..79
            const int j  = j0 + cl;
            if ((ph == 0 || lane < 16) && j < COLS_R) {
                const float* mp = M + (size_t)(4 * q) * COLS_R + j;
                float k0 = __expf(NALPHA * mp[0]);
                float k1 = __expf(NALPHA * mp[COLS_R]);
                float k2 = __expf(NALPHA * mp[2 * COLS_R]);
                float k3 = __expf(NALPHA * mp[3 * COLS_R]);
                int lo = __builtin_amdgcn_cvt_pk_fp8_f32(k0, k1, 0, false);
                int hi = __builtin_amdgcn_cvt_pk_fp8_f32(k2, k3, lo, true);
                sK[cl * CSTR + q] = (uint32)hi;       // dword = rows 4q..4q+3 of col cl
            }
        }
    }
    __syncthreads();

    // ---------------- Sinkhorn loop ----------------
    const float4* u_g4 = reinterpret_cast<const float4*>(u_g);

    for (int t = 1; t <= 100; ++t) {
        // err check folded: iter t's col pass computes K^T u_{t-1} (= err input at cpt=t-1)
        const bool chk  = (t == 2) || (t == 52);
        const int  slot = (t == 52) ? 1 : 0;

        float4 u_r[8];
#pragma unroll
        for (int s = 0; s < 8; ++s) u_r[s] = u_g4[s * 64 + lane];

        // col pass: wave handles 5 of the 80 local columns
        float e = 0.f;
#pragma unroll
        for (int q = 0; q < 5; ++q) {
            const int jl = wav * 5 + q;
            float acc = 0.f;
#pragma unroll
            for (int s = 0; s < 8; ++s) {             // d up to 511: pad/guard are zero, u pad = 0
                uint32 kw = sK[jl * CSTR + s * 64 + lane];
                floatx2 f01 = __builtin_amdgcn_cvt_pk_f32_fp8(kw, false);
                floatx2 f23 = __builtin_amdgcn_cvt_pk_f32_fp8(kw, true);
                acc += f01.x * u_r[s].x + f01.y * u_r[s].y + f23.x * u_r[s].z + f23.y * u_r[s].w;
            }
#pragma unroll
            for (int o = 32; o; o >>= 1) acc += __shfl_xor(acc, o, 64);
            if (lane == 0) {
                float vnew = B_MARG / (acc + EPSV);
                if (chk) {
                    float vold = s_vloc[jl];
                    s_vprev[jl] = vold;               // preserve v_{t-1} for break/loss
                    if (j0 + jl < COLS_R) e += fabsf(vold * acc - B_MARG);
                }
                s_vloc[jl] = vnew;
            }
        }
        if (chk && lane == 0) s_red[wav] = e;
        __syncthreads();                              // v_local ready

        // row partials: wave w owns rows w*128..w*128+127; iterate col pairs
        float4 pa = make_float4(0.f, 0.f, 0.f, 0.f);
#pragma unroll 8
        for (int jp = 0; jp < 40; ++jp) {
            const int cl = 2 * jp + (lane >> 5);
            const int m  = lane & 31;
            uint32 kw = sK[cl * CSTR + wav * 32 + m]; // rows w*128+4m..+3
            float  vv = s_vloc[cl];
            floatx2 f01 = __builtin_amdgcn_cvt_pk_f32_fp8(kw, false);
            floatx2 f23 = __builtin_amdgcn_cvt_pk_f32_fp8(kw, true);
            pa.x += f01.x * vv; pa.y += f01.y * vv;
            pa.z += f23.x * vv; pa.w += f23.y * vv;
        }
        pa.x += __shfl_xor(pa.x, 32, 64);
        pa.y += __shfl_xor(pa.y, 32, 64);
        pa.z += __shfl_xor(pa.z, 32, 64);
        pa.w += __shfl_xor(pa.w, 32, 64);
        if (lane < 32)
            *reinterpret_cast<float4*>(P + (size_t)b * 2048 + wav * 128 + 4 * lane) = pa;

        if (chk && tid == 0) {
            float s = 0.f;
            for (int k = 0; k < NWAVE; ++k) s += s_red[k];
            if (s != 0.f) atomicAdd(&err2[slot], s);
        }
        grid_barrier(ctrl, bar++);

        if (chk) {
            if (tid == 0) s_flag = (err2[slot] <= THR) ? 1 : 0;
            __syncthreads();
            if (s_flag) {                             // converged at cpt=t-1
                if (tid < CPB) s_vloc[tid] = s_vprev[tid];   // restore v_{t-1} for loss
                __syncthreads();
                break;                                // u_g still holds u_{t-1}
            }
        }

        // finalize u: block b owns rows 8b..8b+7; reduce 256 partials per row
        {
            float v0 = P[(size_t)(tid >> 3) * 2048 + 8 * b + (tid & 7)];
            float v1 = P[(size_t)((tid >> 3) + 128) * 2048 + 8 * b + (tid & 7)];
            float s = v0 + v1;
            s += __shfl_xor(s, 8, 64);
            s += __shfl_xor(s, 16, 64);
            s += __shfl_xor(s, 32, 64);
            if (lane < 8) s_red[wav * 8 + lane] = s;  // row slot = lane
        }
        __syncthreads();
        if (tid < 8) {
            float s = 0.f;
            for (int w = 0; w < NWAVE; ++w) s += s_red[w * 8 + tid];
            const int row = 8 * b + tid;
            u_g[row] = (row < ROWS_R) ? A_MARG / (s + EPSV) : 0.0f;  // keep pad zero!
        }
        grid_barrier(ctrl, bar++);
    }

    // ---------------- loss = sum_ij u_i exp(-20 M_ij) v_j M_ij (fp32 from M) ----------------
    {
        float acc = 0.f;
        for (int r = wav; r < ROWS_R; r += NWAVE) {
            const float uu = u_g[r];                  // wave-uniform scalar
            const float* mp = M + (size_t)r * COLS_R + j0;
#pragma unroll
            for (int ph = 0; ph < 2; ++ph) {
                const int cl = ph * 64 + lane;
                if ((ph == 0 || lane < 16) && (j0 + cl) < COLS_R) {
                    float m = mp[cl];
                    acc += uu * __expf(NALPHA * m) * s_vloc[cl] * m;
                }
            }
        }
#pragma unroll
        for (int o = 32; o; o >>= 1) acc += __shfl_xor(acc, o, 64);
        if (lane == 0) s_red[wav] = acc;
        __syncthreads();
        if (tid == 0) {
            float s = 0.f;
            for (int k = 0; k < NWAVE; ++k) s += s_red[k];
            if (s != 0.f) atomicAdd(loss, s);
        }
    }
    grid_barrier(ctrl, bar++);
    if (b == 0 && tid == 0) out[0] = *loss * 100.0f;
}

// ======================= fallback path (tiny workspace) =======================

__device__ __forceinline__ float block_reduce_sum256(float v) {
#pragma unroll
    for (int o = 32; o; o >>= 1) v += __shfl_down(v, o, 64);
    __shared__ float smem[4];
    int lane = threadIdx.x & 63, w = threadIdx.x >> 6;
    if (lane == 0) smem[w] = v;
    __syncthreads();
    v = (threadIdx.x < 4) ? smem[threadIdx.x] : 0.0f;
    v += __shfl_down(v, 2, 64);
    v += __shfl_down(v, 1, 64);
    return v;
}

__global__ __launch_bounds__(256) void fb_init(float* u, float* vden, int* done, float* err, float* loss) {
    int idx = blockIdx.x * 256 + threadIdx.x;
    if (idx == 0) { *done = 0; *err = 0.0f; *loss = 0.0f; }
    if (idx < ROWS_R) u[idx] = A_MARG;
    if (idx < COLS_R) vden[idx] = 0.0f;
}
__global__ __launch_bounds__(256) void fb_colpass(const float* __restrict__ M, const float* __restrict__ u,
                                                  float* __restrict__ vden, const int* __restrict__ done) {
    if (*done) return;
    int c4 = blockIdx.x * 256 + threadIdx.x;
    if (c4 >= 5000) return;
    int r0 = blockIdx.y * 50;
    float4 acc = make_float4(0.f, 0.f, 0.f, 0.f);
    for (int r = r0; r < r0 + 50; ++r) {
        float ui = u[r];
        float4 mm = reinterpret_cast<const float4*>(M)[(size_t)r * 5000 + c4];
        acc.x += __expf(NALPHA * mm.x) * ui; acc.y += __expf(NALPHA * mm.y) * ui;
        acc.z += __expf(NALPHA * mm.z) * ui; acc.w += __expf(NALPHA * mm.w) * ui;
    }
    atomicAdd(&vden[c4 * 4 + 0], acc.x); atomicAdd(&vden[c4 * 4 + 1], acc.y);
    atomicAdd(&vden[c4 * 4 + 2], acc.z); atomicAdd(&vden[c4 * 4 + 3], acc.w);
}
__global__ __launch_bounds__(256) void fb_finv(float* v, float* vden, const int* done) {
    if (*done) return;
    int j = blockIdx.x * 256 + threadIdx.x;
    if (j < COLS_R) { v[j] = B_MARG / (vden[j] + EPSV); vden[j] = 0.0f; }
}
__global__ __launch_bounds__(256) void fb_rowpass(const float* __restrict__ M, const float* __restrict__ v,
                                                  float* __restrict__ u, const int* __restrict__ done) {
    if (*done) return;
    int row = blockIdx.x;
    const float4* v4 = reinterpret_cast<const float4*>(v);
    float acc = 0.0f;
    for (int c4 = threadIdx.x; c4 < 5000; c4 += 256) {
        float4 mm = reinterpret_cast<const float4*>(M)[(size_t)row * 5000 + c4];
        float4 vv = v4[c4];
        acc += __expf(NALPHA * mm.x) * vv.x + __expf(NALPHA * mm.y) * vv.y
             + __expf(NALPHA * mm.z) * vv.z + __expf(NALPHA * mm.w) * vv.w;
    }
    float s = block_reduce_sum256(acc);
    if (threadIdx.x == 0) u[row] = A_MARG / (s + EPSV);
}
__global__ __launch_bounds__(256) void fb_errfin(const float* v, float* vden, float* err, const int* done) {
    if (*done) return;
    int j = blockIdx.x * 256 + threadIdx.x;
    float local = 0.0f;
    if (j < COLS_R) { local = fabsf(v[j] * vden[j] - B_MARG); vden[j] = 0.0f; }
    float s = block_reduce_sum256(local);
    if (threadIdx.x == 0) atomicAdd(err, s);
}
__global__ void fb_check(int* done, float* err) {
    if (threadIdx.x == 0) { if (!*done && *err <= THR) *done = 1; *err = 0.0f; }
}
__global__ __launch_bounds__(256) void fb_loss(const float* __restrict__ M, const float* __restrict__ u,
                                               const float* __restrict__ v, float* __restrict__ loss) {
    int row = blockIdx.x;
    const float4* M4p = reinterpret_cast<const float4*>(M + (size_t)row * COLS_R);
    const float4* v4 = reinterpret_cast<const float4*>(v);
    float acc = 0.0f;
    for (int c4 = threadIdx.x; c4 < 5000; c4 += 256) {
        float4 mm = M4p[c4]; float4 vv = v4[c4];
        acc += __expf(NALPHA * mm.x) * vv.x * mm.x + __expf(NALPHA * mm.y) * vv.y * mm.y
             + __expf(NALPHA * mm.z) * vv.z * mm.z + __expf(NALPHA * mm.w) * vv.w * mm.w;
    }
    float s = block_reduce_sum256(acc);
    if (threadIdx.x == 0) atomicAdd(loss, s * u[row]);
}
__global__ void fb_writeout(float* out, const float* loss) {
    if (threadIdx.x == 0) out[0] = *loss * 100.0f;
}

// ======================= host launch =======================

extern "C" void kernel_launch(void* const* d_in, const int* in_sizes, int n_in,
                              void* d_out, int out_size, void* d_ws, size_t ws_size,
                              hipStream_t stream) {
    const float* M = (const float*)d_in[0];
    char* base = (char*)d_ws;

    const size_t OFF_CTRL = 0;                        // uint32[2048] (8 KB; 1280 used)
    const size_t OFF_ERR  = 8192;
    const size_t OFF_LOSS = 8320;
    const size_t OFF_U    = 8448;                     // 2048 floats (16B aligned)
    const size_t OFF_P    = OFF_U + 8192 + 256;       // 256 x 2048 floats
    const size_t NEED     = OFF_P + (size_t)NBLK * 2048 * 4;   // ~2.1 MB

    if (ws_size >= NEED) {
        uint32* ctrl = (uint32*)(base + OFF_CTRL);
        float*  err2 = (float*)(base + OFF_ERR);
        float*  loss = (float*)(base + OFF_LOSS);
        float*  u_g  = (float*)(base + OFF_U);
        float*  P    = (float*)(base + OFF_P);

        init_kernel<<<8, 256, 0, stream>>>(u_g, ctrl, err2, loss);
        sinkhorn_lds<<<NBLK, NTHR, 0, stream>>>(M, u_g, P, ctrl, err2, loss, (float*)d_out);
    } else {
        int*   done = (int*)(base + 0);
        float* err  = (float*)(base + 8);
        float* loss = (float*)(base + 16);
        float* u    = (float*)(base + 64);
        float* v    = (float*)(base + 64 + 8192);
        float* vden = (float*)(base + 64 + 8192 + 80000);

        fb_init<<<79, 256, 0, stream>>>(u, vden, done, err, loss);
        dim3 cgrid(20, 40);
        for (int t = 1; t <= 100; ++t) {
            fb_colpass<<<cgrid, 256, 0, stream>>>(M, u, vden, done);
            fb_finv<<<79, 256, 0, stream>>>(v, vden, done);
            fb_rowpass<<<ROWS_R, 256, 0, stream>>>(M, v, u, done);
            if (t == 1 || t == 51) {
                fb_colpass<<<cgrid, 256, 0, stream>>>(M, u, vden, done);
                fb_errfin<<<79, 256, 0, stream>>>(v, vden, err, done);
                fb_check<<<1, 64, 0, stream>>>(done, err);
            }
        }
        fb_loss<<<ROWS_R, 256, 0, stream>>>(M, u, v, loss);
        fb_writeout<<<1, 64, 0, stream>>>((float*)d_out, loss);
    }
}